// Round 1
// baseline (975.440 us; speedup 1.0000x reference)
//
#include <hip/hip_runtime.h>
#include <hip/hip_bf16.h>

#define NEG_SLOPE 0.2f

// ---------------------------------------------------------------------------
// Utility: zero an int buffer
// ---------------------------------------------------------------------------
__global__ void zero_int_kernel(int* __restrict__ p, int n) {
    int i = blockIdx.x * blockDim.x + threadIdx.x;
    if (i < n) p[i] = 0;
}

// ---------------------------------------------------------------------------
// A1: layer-1 node transforms.  x:[N,6] -> xlp,xrp:[N,64] of float2 (head0,head1)
// thread = (node, channel)
// ---------------------------------------------------------------------------
__global__ void __launch_bounds__(256) a1_kernel(
    const float* __restrict__ x,
    const float* __restrict__ Wl1, const float* __restrict__ bl1,
    const float* __restrict__ Wr1, const float* __restrict__ br1,
    float2* __restrict__ xlp, float2* __restrict__ xrp, int N)
{
    int gt = blockIdx.x * blockDim.x + threadIdx.x;
    int n = gt >> 6, c = gt & 63;
    if (n >= N) return;
    const float* xrow = x + (size_t)n * 6;
    float l0 = bl1[c], l1 = bl1[64 + c];
    float r0 = br1[c], r1 = br1[64 + c];
#pragma unroll
    for (int f = 0; f < 6; ++f) {
        float xv = xrow[f];
        l0 = fmaf(xv, Wl1[f * 128 + c], l0);
        l1 = fmaf(xv, Wl1[f * 128 + 64 + c], l1);
        r0 = fmaf(xv, Wr1[f * 128 + c], r0);
        r1 = fmaf(xv, Wr1[f * 128 + 64 + c], r1);
    }
    xlp[(size_t)n * 64 + c] = make_float2(l0, l1);
    xrp[(size_t)n * 64 + c] = make_float2(r0, r1);
}

// ---------------------------------------------------------------------------
// CSR build: histogram of dst, two-level exclusive scan, scatter
// ---------------------------------------------------------------------------
__global__ void hist_kernel(const int* __restrict__ dstv, int* __restrict__ deg, int E) {
    int e = blockIdx.x * blockDim.x + threadIdx.x;
    if (e < E) atomicAdd(&deg[dstv[e]], 1);
}

__global__ void scan1_kernel(const int* __restrict__ deg, int* __restrict__ bsum, int N) {
    __shared__ int red[256];
    int b = blockIdx.x, t = threadIdx.x;
    int i0 = b * 512 + t, i1 = i0 + 256;
    int v = 0;
    if (i0 < N) v += deg[i0];
    if (i1 < N) v += deg[i1];
    red[t] = v;
    __syncthreads();
    for (int s = 128; s > 0; s >>= 1) {
        if (t < s) red[t] += red[t + s];
        __syncthreads();
    }
    if (t == 0) bsum[b] = red[0];
}

__global__ void scan2_kernel(const int* __restrict__ bsum, int* __restrict__ bpref,
                             int* __restrict__ off, int B, int N) {
    __shared__ int lds[1024];
    int t = threadIdx.x;
    for (int i = t; i < B; i += blockDim.x) lds[i] = bsum[i];
    __syncthreads();
    if (t == 0) {
        int run = 0;
        for (int i = 0; i < B; ++i) { int v = lds[i]; lds[i] = run; run += v; }
        off[N] = run;   // == E
    }
    __syncthreads();
    for (int i = t; i < B; i += blockDim.x) bpref[i] = lds[i];
}

__global__ void scan3_kernel(const int* __restrict__ deg, const int* __restrict__ bpref,
                             int* __restrict__ off, int* __restrict__ pos, int N) {
    __shared__ int lds[512];
    int b = blockIdx.x, t = threadIdx.x;
    int base = b * 512;
    for (int i = t; i < 512; i += 256) {
        int g = base + i;
        lds[i] = (g < N) ? deg[g] : 0;
    }
    __syncthreads();
    if (t == 0) {
        int run = bpref[b];
        for (int i = 0; i < 512; ++i) { int v = lds[i]; lds[i] = run; run += v; }
    }
    __syncthreads();
    for (int i = t; i < 512; i += 256) {
        int g = base + i;
        if (g < N) { off[g] = lds[i]; pos[g] = lds[i]; }
    }
}

__global__ void scatter_kernel(const int* __restrict__ srcv, const int* __restrict__ dstv,
                               const float2* __restrict__ ea2, int* __restrict__ pos,
                               int* __restrict__ csr_src, float2* __restrict__ csr_ea, int E) {
    int e = blockIdx.x * blockDim.x + threadIdx.x;
    if (e >= E) return;
    int d = dstv[e];
    int p = atomicAdd(&pos[d], 1);
    csr_src[p] = srcv[e];
    csr_ea[p] = ea2[e];
}

// ---------------------------------------------------------------------------
// C1: layer-1 per-dst-node aggregation (wave per node, online softmax)
// writes h1:[N,128] = relu(agg + bias1)
// ---------------------------------------------------------------------------
__global__ void __launch_bounds__(256) c1_kernel(
    const int* __restrict__ off, const int* __restrict__ csr_src,
    const float2* __restrict__ csr_ea,
    const float2* __restrict__ xlp, const float2* __restrict__ xrp,
    const float* __restrict__ We1, const float* __restrict__ att1,
    const float* __restrict__ bias1,
    float* __restrict__ h1, int N)
{
    int wid = (blockIdx.x * blockDim.x + threadIdx.x) >> 6;
    int lane = threadIdx.x & 63;
    if (wid >= N) return;
    int n = wid;

    float2 xr = xrp[(size_t)n * 64 + lane];
    float a0 = att1[lane], a1 = att1[64 + lane];
    float w00 = We1[lane],       w01 = We1[64 + lane];    // We1[0][h*64+c]
    float w10 = We1[128 + lane], w11 = We1[192 + lane];   // We1[1][h*64+c]

    int s = off[n], e = off[n + 1];
    float m0 = -3.0e38f, m1 = -3.0e38f;
    float d0 = 0.f, d1 = 0.f, acc0 = 0.f, acc1 = 0.f;

    for (int p = s; p < e; ++p) {
        int src = csr_src[p];
        float2 ea = csr_ea[p];
        float2 xl = xlp[(size_t)src * 64 + lane];
        float g0 = xl.x + xr.x + fmaf(ea.x, w00, ea.y * w10);
        float g1 = xl.y + xr.y + fmaf(ea.x, w01, ea.y * w11);
        g0 = (g0 >= 0.f) ? g0 : NEG_SLOPE * g0;
        g1 = (g1 >= 0.f) ? g1 : NEG_SLOPE * g1;
        float p0 = g0 * a0, p1 = g1 * a1;
#pragma unroll
        for (int o = 32; o; o >>= 1) {
            p0 += __shfl_xor(p0, o);
            p1 += __shfl_xor(p1, o);
        }
        float nm0 = fmaxf(m0, p0), nm1 = fmaxf(m1, p1);
        float s0 = __expf(m0 - nm0), s1 = __expf(m1 - nm1);
        float e0 = __expf(p0 - nm0), e1 = __expf(p1 - nm1);
        d0 = fmaf(d0, s0, e0);
        d1 = fmaf(d1, s1, e1);
        acc0 = fmaf(acc0, s0, e0 * xl.x);
        acc1 = fmaf(acc1, s1, e1 * xl.y);
        m0 = nm0; m1 = nm1;
    }

    float o0 = acc0 / (d0 + 1e-16f) + bias1[lane];
    float o1 = acc1 / (d1 + 1e-16f) + bias1[64 + lane];
    o0 = fmaxf(o0, 0.f);
    o1 = fmaxf(o1, 0.f);
    h1[(size_t)n * 128 + lane] = o0;
    h1[(size_t)n * 128 + 64 + lane] = o1;
}

// ---------------------------------------------------------------------------
// A2: layer-2 node transforms. h1:[N,128] @ Wl2/Wr2:[128,64] (+bias)
// wave handles 8 nodes; weight rows coalesced, h1 broadcast via shuffles
// ---------------------------------------------------------------------------
__global__ void __launch_bounds__(256) a2_kernel(
    const float* __restrict__ h1,
    const float* __restrict__ Wl2, const float* __restrict__ bl2,
    const float* __restrict__ Wr2, const float* __restrict__ br2,
    float* __restrict__ xl2, float* __restrict__ xr2, int N)
{
    int wid = (blockIdx.x * blockDim.x + threadIdx.x) >> 6;
    int lane = threadIdx.x & 63;
    int n0 = wid * 8;
    if (n0 >= N) return;

    float hl[8], hh[8], aL[8], aR[8];
#pragma unroll
    for (int j = 0; j < 8; ++j) {
        int n = n0 + j;
        bool v = (n < N);
        hl[j] = v ? h1[(size_t)n * 128 + lane] : 0.f;
        hh[j] = v ? h1[(size_t)n * 128 + 64 + lane] : 0.f;
        aL[j] = bl2[lane];
        aR[j] = br2[lane];
    }
    for (int k = 0; k < 64; ++k) {
        float wl = Wl2[k * 64 + lane];
        float wr = Wr2[k * 64 + lane];
#pragma unroll
        for (int j = 0; j < 8; ++j) {
            float hv = __shfl(hl[j], k);
            aL[j] = fmaf(hv, wl, aL[j]);
            aR[j] = fmaf(hv, wr, aR[j]);
        }
    }
    for (int k = 0; k < 64; ++k) {
        float wl = Wl2[(64 + k) * 64 + lane];
        float wr = Wr2[(64 + k) * 64 + lane];
#pragma unroll
        for (int j = 0; j < 8; ++j) {
            float hv = __shfl(hh[j], k);
            aL[j] = fmaf(hv, wl, aL[j]);
            aR[j] = fmaf(hv, wr, aR[j]);
        }
    }
#pragma unroll
    for (int j = 0; j < 8; ++j) {
        int n = n0 + j;
        if (n < N) {
            xl2[(size_t)n * 64 + lane] = aL[j];
            xr2[(size_t)n * 64 + lane] = aR[j];
        }
    }
}

// ---------------------------------------------------------------------------
// C2: layer-2 aggregation (wave per node) + fused MLP head -> out[N]
// ---------------------------------------------------------------------------
__global__ void __launch_bounds__(256) c2_kernel(
    const int* __restrict__ off, const int* __restrict__ csr_src,
    const float2* __restrict__ csr_ea,
    const float* __restrict__ xl2, const float* __restrict__ xr2,
    const float* __restrict__ We2, const float* __restrict__ att2,
    const float* __restrict__ bias2,
    const float* __restrict__ Wh1, const float* __restrict__ bh1,
    const float* __restrict__ Wh2, const float* __restrict__ bh2,
    float* __restrict__ out, int N)
{
    __shared__ float wh1s[64 * 64];
    __shared__ float wh2s[64];
    __shared__ float bh1s[64];
    for (int i = threadIdx.x; i < 64 * 64; i += 256) wh1s[i] = Wh1[i];
    if (threadIdx.x < 64) {
        wh2s[threadIdx.x] = Wh2[threadIdx.x];
        bh1s[threadIdx.x] = bh1[threadIdx.x];
    }
    __syncthreads();

    int wid = (blockIdx.x * blockDim.x + threadIdx.x) >> 6;
    int lane = threadIdx.x & 63;
    if (wid >= N) return;
    int n = wid;

    float xr = xr2[(size_t)n * 64 + lane];
    float av = att2[lane];
    float w0 = We2[lane], w1 = We2[64 + lane];

    int s = off[n], e = off[n + 1];
    float m = -3.0e38f, d = 0.f, acc = 0.f;

    for (int p = s; p < e; ++p) {
        int src = csr_src[p];
        float2 ea = csr_ea[p];
        float xl = xl2[(size_t)src * 64 + lane];
        float g = xl + xr + fmaf(ea.x, w0, ea.y * w1);
        g = (g >= 0.f) ? g : NEG_SLOPE * g;
        float pv = g * av;
#pragma unroll
        for (int o = 32; o; o >>= 1) pv += __shfl_xor(pv, o);
        float nm = fmaxf(m, pv);
        float sc = __expf(m - nm);
        float ev = __expf(pv - nm);
        d = fmaf(d, sc, ev);
        acc = fmaf(acc, sc, ev * xl);
        m = nm;
    }

    float h2v = acc / (d + 1e-16f) + bias2[lane];
    h2v = fmaxf(h2v, 0.f);

    // MLP head: t_j = relu(sum_l h2[l]*Wh1[l][j] + bh1[j]); out = sum_j t_j*Wh2[j] + bh2
    float t = bh1s[lane];
    for (int l = 0; l < 64; ++l) {
        float hv = __shfl(h2v, l);
        t = fmaf(hv, wh1s[l * 64 + lane], t);
    }
    t = fmaxf(t, 0.f);
    float partial = t * wh2s[lane];
#pragma unroll
    for (int o = 32; o; o >>= 1) partial += __shfl_xor(partial, o);
    if (lane == 0) out[n] = partial + bh2[0];
}

// ---------------------------------------------------------------------------
// launch
// ---------------------------------------------------------------------------
extern "C" void kernel_launch(void* const* d_in, const int* in_sizes, int n_in,
                              void* d_out, int out_size, void* d_ws, size_t ws_size,
                              hipStream_t stream) {
    const float* x    = (const float*)d_in[0];
    const int*   ei   = (const int*)d_in[1];
    const float* ea   = (const float*)d_in[2];
    const float* Wl1  = (const float*)d_in[3];
    const float* bl1  = (const float*)d_in[4];
    const float* Wr1  = (const float*)d_in[5];
    const float* br1  = (const float*)d_in[6];
    const float* We1  = (const float*)d_in[7];
    const float* att1 = (const float*)d_in[8];
    const float* bias1= (const float*)d_in[9];
    const float* Wl2  = (const float*)d_in[10];
    const float* bl2  = (const float*)d_in[11];
    const float* Wr2  = (const float*)d_in[12];
    const float* br2  = (const float*)d_in[13];
    const float* We2  = (const float*)d_in[14];
    const float* att2 = (const float*)d_in[15];
    const float* bias2= (const float*)d_in[16];
    const float* Wh1  = (const float*)d_in[17];
    const float* bh1  = (const float*)d_in[18];
    const float* Wh2  = (const float*)d_in[19];
    const float* bh2  = (const float*)d_in[20];

    int N = in_sizes[0] / 6;
    int E = in_sizes[1] / 2;
    const int* srcv = ei;
    const int* dstv = ei + E;

    // workspace layout
    char* w = (char*)d_ws;
    size_t szN128 = (size_t)N * 128 * sizeof(float);
    float2* xlp = (float2*)(w);                 // region 0 (later reused by xl2)
    float2* xrp = (float2*)(w + szN128);        // region 1 (later reused by xr2)
    float*  h1  = (float*)(w + 2 * szN128);     // region 2
    float*  xl2 = (float*)(w);                  // reuse region 0 after c1
    float*  xr2 = (float*)(w + szN128);         // reuse region 1 after c1

    char* ip = w + 3 * szN128;
    auto align256 = [](size_t v) { return (v + 255) & ~(size_t)255; };
    int* deg = (int*)ip;  ip += align256((size_t)N * 4);
    int* off = (int*)ip;  ip += align256((size_t)(N + 1) * 4);
    int* pos = (int*)ip;  ip += align256((size_t)N * 4);
    int B = (N + 511) / 512;
    int* bsum  = (int*)ip; ip += align256((size_t)B * 4);
    int* bpref = (int*)ip; ip += align256((size_t)B * 4);
    int* csr_src = (int*)ip;    ip += align256((size_t)E * 4);
    float2* csr_ea = (float2*)ip;

    // 1. zero degree counts
    zero_int_kernel<<<(N + 255) / 256, 256, 0, stream>>>(deg, N);
    // 2. layer-1 node transforms
    a1_kernel<<<((size_t)N * 64 + 255) / 256, 256, 0, stream>>>(
        x, Wl1, bl1, Wr1, br1, xlp, xrp, N);
    // 3. CSR build
    hist_kernel<<<(E + 255) / 256, 256, 0, stream>>>(dstv, deg, E);
    scan1_kernel<<<B, 256, 0, stream>>>(deg, bsum, N);
    scan2_kernel<<<1, 256, 0, stream>>>(bsum, bpref, off, B, N);
    scan3_kernel<<<B, 256, 0, stream>>>(deg, bpref, off, pos, N);
    scatter_kernel<<<(E + 255) / 256, 256, 0, stream>>>(
        srcv, dstv, (const float2*)ea, pos, csr_src, csr_ea, E);
    // 4. layer-1 aggregation -> h1
    c1_kernel<<<((size_t)N * 64 + 255) / 256, 256, 0, stream>>>(
        off, csr_src, csr_ea, xlp, xrp, We1, att1, bias1, h1, N);
    // 5. layer-2 node transforms
    {
        int waves = (N + 7) / 8;
        a2_kernel<<<((size_t)waves * 64 + 255) / 256, 256, 0, stream>>>(
            h1, Wl2, bl2, Wr2, br2, xl2, xr2, N);
    }
    // 6. layer-2 aggregation + fused MLP head -> out
    c2_kernel<<<((size_t)N * 64 + 255) / 256, 256, 0, stream>>>(
        off, csr_src, csr_ea, xl2, xr2, We2, att2, bias2,
        Wh1, bh1, Wh2, bh2, (float*)d_out, N);
}

// Round 2
// 776.390 us; speedup vs baseline: 1.2564x; 1.2564x over previous
//
#include <hip/hip_runtime.h>
#include <hip/hip_bf16.h>

#define NEG_SLOPE 0.2f

__device__ __forceinline__ void ld4(float* d, const float* p) {
    float4 t = *(const float4*)p;
    d[0] = t.x; d[1] = t.y; d[2] = t.z; d[3] = t.w;
}

// ---------------------------------------------------------------------------
__global__ void zero_int_kernel(int* __restrict__ p, int n) {
    int i = blockIdx.x * blockDim.x + threadIdx.x;
    if (i < n) p[i] = 0;
}

// ---------------------------------------------------------------------------
// A1: layer-1 source-side transform only (xr computed inline in c1).
// x:[N,6] -> xl0t,xl1t:[N,64] planar (head0, head1)
// ---------------------------------------------------------------------------
__global__ void __launch_bounds__(256) a1_kernel(
    const float* __restrict__ x,
    const float* __restrict__ Wl1, const float* __restrict__ bl1,
    float* __restrict__ xl0t, float* __restrict__ xl1t, int N)
{
    int gt = blockIdx.x * blockDim.x + threadIdx.x;
    int n = gt >> 6, c = gt & 63;
    if (n >= N) return;
    const float* xrow = x + (size_t)n * 6;
    float l0 = bl1[c], l1 = bl1[64 + c];
#pragma unroll
    for (int f = 0; f < 6; ++f) {
        float xv = xrow[f];
        l0 = fmaf(xv, Wl1[f * 128 + c], l0);
        l1 = fmaf(xv, Wl1[f * 128 + 64 + c], l1);
    }
    xl0t[(size_t)n * 64 + c] = l0;
    xl1t[(size_t)n * 64 + c] = l1;
}

// ---------------------------------------------------------------------------
// CSR build
// ---------------------------------------------------------------------------
__global__ void hist_kernel(const int* __restrict__ dstv, int* __restrict__ deg, int E) {
    int e = blockIdx.x * blockDim.x + threadIdx.x;
    if (e < E) atomicAdd(&deg[dstv[e]], 1);
}

__global__ void scan1_kernel(const int* __restrict__ deg, int* __restrict__ bsum, int N) {
    __shared__ int red[256];
    int b = blockIdx.x, t = threadIdx.x;
    int i0 = b * 512 + t, i1 = i0 + 256;
    int v = 0;
    if (i0 < N) v += deg[i0];
    if (i1 < N) v += deg[i1];
    red[t] = v;
    __syncthreads();
    for (int s = 128; s > 0; s >>= 1) {
        if (t < s) red[t] += red[t + s];
        __syncthreads();
    }
    if (t == 0) bsum[b] = red[0];
}

__global__ void scan2_kernel(const int* __restrict__ bsum, int* __restrict__ bpref,
                             int* __restrict__ off, int B, int N) {
    __shared__ int lds[1024];
    int t = threadIdx.x;
    for (int i = t; i < B; i += blockDim.x) lds[i] = bsum[i];
    __syncthreads();
    if (t == 0) {
        int run = 0;
        for (int i = 0; i < B; ++i) { int v = lds[i]; lds[i] = run; run += v; }
        off[N] = run;
    }
    __syncthreads();
    for (int i = t; i < B; i += blockDim.x) bpref[i] = lds[i];
}

__global__ void scan3_kernel(const int* __restrict__ deg, const int* __restrict__ bpref,
                             int* __restrict__ off, int* __restrict__ pos, int N) {
    __shared__ int lds[512];
    int b = blockIdx.x, t = threadIdx.x;
    int base = b * 512;
    for (int i = t; i < 512; i += 256) {
        int g = base + i;
        lds[i] = (g < N) ? deg[g] : 0;
    }
    __syncthreads();
    if (t == 0) {
        int run = bpref[b];
        for (int i = 0; i < 512; ++i) { int v = lds[i]; lds[i] = run; run += v; }
    }
    __syncthreads();
    for (int i = t; i < 512; i += 256) {
        int g = base + i;
        if (g < N) { off[g] = lds[i]; pos[g] = lds[i]; }
    }
}

// one scattered 16B write per edge: {src, ea.x, ea.y, pad}
__global__ void scatter_kernel(const int* __restrict__ srcv, const int* __restrict__ dstv,
                               const float2* __restrict__ ea2, int* __restrict__ pos,
                               int4* __restrict__ csr_edge, int E) {
    int e = blockIdx.x * blockDim.x + threadIdx.x;
    if (e >= E) return;
    int d = dstv[e];
    int p = atomicAdd(&pos[d], 1);
    float2 ea = ea2[e];
    int4 v;
    v.x = srcv[e];
    v.y = __float_as_int(ea.x);
    v.z = __float_as_int(ea.y);
    v.w = 0;
    csr_edge[p] = v;
}

// ---------------------------------------------------------------------------
// C1: layer-1 aggregation. Wave per dst node; 4 edges/iter x 16 lanes/edge,
// each lane owns 4 channels (both heads). xr computed inline from x.
// ---------------------------------------------------------------------------
__global__ void __launch_bounds__(256) c1_kernel(
    const int* __restrict__ off, const int4* __restrict__ csr_edge,
    const float* __restrict__ xl0t, const float* __restrict__ xl1t,
    const float* __restrict__ x,
    const float* __restrict__ Wr1, const float* __restrict__ br1,
    const float* __restrict__ We1, const float* __restrict__ att1,
    const float* __restrict__ bias1,
    float* __restrict__ h1, int N)
{
    int wid = (blockIdx.x * blockDim.x + threadIdx.x) >> 6;
    int lane = threadIdx.x & 63;
    if (wid >= N) return;
    int n = wid;
    int g = lane & 15;
    int slot = lane >> 4;

    // per-lane constants for channels 4g..4g+3
    float a0[4], a1[4], w00[4], w01[4], w10[4], w11[4];
    ld4(a0, att1 + 4 * g);
    ld4(a1, att1 + 64 + 4 * g);
    ld4(w00, We1 + 4 * g);          // ea.x weights, head0
    ld4(w01, We1 + 64 + 4 * g);     // ea.x weights, head1
    ld4(w10, We1 + 128 + 4 * g);    // ea.y weights, head0
    ld4(w11, We1 + 192 + 4 * g);    // ea.y weights, head1

    // xr inline: xr = x[n] @ Wr1 + br1 (6-dim input)
    float xr0[4], xr1[4];
    ld4(xr0, br1 + 4 * g);
    ld4(xr1, br1 + 64 + 4 * g);
    {
        const float* xrow = x + (size_t)n * 6;
#pragma unroll
        for (int f = 0; f < 6; ++f) {
            float xv = xrow[f];
            float wa[4], wb[4];
            ld4(wa, Wr1 + f * 128 + 4 * g);
            ld4(wb, Wr1 + f * 128 + 64 + 4 * g);
#pragma unroll
            for (int i = 0; i < 4; ++i) {
                xr0[i] = fmaf(xv, wa[i], xr0[i]);
                xr1[i] = fmaf(xv, wb[i], xr1[i]);
            }
        }
    }

    int s = off[n], e = off[n + 1];
    float m0 = -3.0e38f, m1 = -3.0e38f, d0 = 0.f, d1 = 0.f;
    float acc0[4] = {0, 0, 0, 0}, acc1[4] = {0, 0, 0, 0};

#pragma unroll 2
    for (int p0 = s; p0 < e; p0 += 4) {
        int p = p0 + slot;
        bool valid = (p < e);
        int4 ed = csr_edge[valid ? p : p0];
        int src = ed.x;
        float eax = __int_as_float(ed.y), eay = __int_as_float(ed.z);
        float xl0[4], xl1[4];
        ld4(xl0, xl0t + (size_t)src * 64 + 4 * g);
        ld4(xl1, xl1t + (size_t)src * 64 + 4 * g);

        float p0v = 0.f, p1v = 0.f;
#pragma unroll
        for (int i = 0; i < 4; ++i) {
            float g0 = xl0[i] + xr0[i] + fmaf(eax, w00[i], eay * w10[i]);
            float g1 = xl1[i] + xr1[i] + fmaf(eax, w01[i], eay * w11[i]);
            g0 = fmaxf(g0, NEG_SLOPE * g0);
            g1 = fmaxf(g1, NEG_SLOPE * g1);
            p0v = fmaf(g0, a0[i], p0v);
            p1v = fmaf(g1, a1[i], p1v);
        }
        // reduce over the 16 lanes of this edge slot (both heads together)
        p0v += __shfl_xor(p0v, 1);  p1v += __shfl_xor(p1v, 1);
        p0v += __shfl_xor(p0v, 2);  p1v += __shfl_xor(p1v, 2);
        p0v += __shfl_xor(p0v, 4);  p1v += __shfl_xor(p1v, 4);
        p0v += __shfl_xor(p0v, 8);  p1v += __shfl_xor(p1v, 8);
        float l0 = valid ? p0v : -3.0e38f;
        float l1 = valid ? p1v : -3.0e38f;
        // batch max across the 4 slots -> wave-uniform
        float bm0 = fmaxf(l0, __shfl_xor(l0, 16)); bm0 = fmaxf(bm0, __shfl_xor(bm0, 32));
        float bm1 = fmaxf(l1, __shfl_xor(l1, 16)); bm1 = fmaxf(bm1, __shfl_xor(bm1, 32));
        float nm0 = fmaxf(m0, bm0), nm1 = fmaxf(m1, bm1);
        float sc0 = __expf(m0 - nm0), sc1 = __expf(m1 - nm1);
        float e0 = __expf(l0 - nm0), e1 = __expf(l1 - nm1);
        d0 = fmaf(d0, sc0, e0);
        d1 = fmaf(d1, sc1, e1);
#pragma unroll
        for (int i = 0; i < 4; ++i) {
            acc0[i] = fmaf(acc0[i], sc0, e0 * xl0[i]);
            acc1[i] = fmaf(acc1[i], sc1, e1 * xl1[i]);
        }
        m0 = nm0; m1 = nm1;
    }

    // combine the 4 slots' partial sums
#pragma unroll
    for (int i = 0; i < 4; ++i) {
        acc0[i] += __shfl_xor(acc0[i], 16); acc0[i] += __shfl_xor(acc0[i], 32);
        acc1[i] += __shfl_xor(acc1[i], 16); acc1[i] += __shfl_xor(acc1[i], 32);
    }
    d0 += __shfl_xor(d0, 16); d0 += __shfl_xor(d0, 32);
    d1 += __shfl_xor(d1, 16); d1 += __shfl_xor(d1, 32);

    if (slot == 0) {
        float b0[4], b1[4];
        ld4(b0, bias1 + 4 * g);
        ld4(b1, bias1 + 64 + 4 * g);
        float r0 = 1.f / (d0 + 1e-16f), r1 = 1.f / (d1 + 1e-16f);
        float4 o0, o1;
        o0.x = fmaxf(fmaf(acc0[0], r0, b0[0]), 0.f);
        o0.y = fmaxf(fmaf(acc0[1], r0, b0[1]), 0.f);
        o0.z = fmaxf(fmaf(acc0[2], r0, b0[2]), 0.f);
        o0.w = fmaxf(fmaf(acc0[3], r0, b0[3]), 0.f);
        o1.x = fmaxf(fmaf(acc1[0], r1, b1[0]), 0.f);
        o1.y = fmaxf(fmaf(acc1[1], r1, b1[1]), 0.f);
        o1.z = fmaxf(fmaf(acc1[2], r1, b1[2]), 0.f);
        o1.w = fmaxf(fmaf(acc1[3], r1, b1[3]), 0.f);
        *(float4*)(h1 + (size_t)n * 128 + 4 * g) = o0;
        *(float4*)(h1 + (size_t)n * 128 + 64 + 4 * g) = o1;
    }
}

// ---------------------------------------------------------------------------
// A2: layer-2 node transforms. h1:[N,128] @ Wl2/Wr2:[128,64] (+bias)
// ---------------------------------------------------------------------------
__global__ void __launch_bounds__(256) a2_kernel(
    const float* __restrict__ h1,
    const float* __restrict__ Wl2, const float* __restrict__ bl2,
    const float* __restrict__ Wr2, const float* __restrict__ br2,
    float* __restrict__ xl2, float* __restrict__ xr2, int N)
{
    int wid = (blockIdx.x * blockDim.x + threadIdx.x) >> 6;
    int lane = threadIdx.x & 63;
    int n0 = wid * 8;
    if (n0 >= N) return;

    float hl[8], hh[8], aL[8], aR[8];
#pragma unroll
    for (int j = 0; j < 8; ++j) {
        int n = n0 + j;
        bool v = (n < N);
        hl[j] = v ? h1[(size_t)n * 128 + lane] : 0.f;
        hh[j] = v ? h1[(size_t)n * 128 + 64 + lane] : 0.f;
        aL[j] = bl2[lane];
        aR[j] = br2[lane];
    }
    for (int k = 0; k < 64; ++k) {
        float wl = Wl2[k * 64 + lane];
        float wr = Wr2[k * 64 + lane];
#pragma unroll
        for (int j = 0; j < 8; ++j) {
            float hv = __shfl(hl[j], k);
            aL[j] = fmaf(hv, wl, aL[j]);
            aR[j] = fmaf(hv, wr, aR[j]);
        }
    }
    for (int k = 0; k < 64; ++k) {
        float wl = Wl2[(64 + k) * 64 + lane];
        float wr = Wr2[(64 + k) * 64 + lane];
#pragma unroll
        for (int j = 0; j < 8; ++j) {
            float hv = __shfl(hh[j], k);
            aL[j] = fmaf(hv, wl, aL[j]);
            aR[j] = fmaf(hv, wr, aR[j]);
        }
    }
#pragma unroll
    for (int j = 0; j < 8; ++j) {
        int n = n0 + j;
        if (n < N) {
            xl2[(size_t)n * 64 + lane] = aL[j];
            xr2[(size_t)n * 64 + lane] = aR[j];
        }
    }
}

// ---------------------------------------------------------------------------
// C2: layer-2 aggregation + fused MLP head. Same 16x4 wave mapping.
// No LDS, no barriers: Wh1 (16KB) is L1-resident.
// ---------------------------------------------------------------------------
__global__ void __launch_bounds__(256) c2_kernel(
    const int* __restrict__ off, const int4* __restrict__ csr_edge,
    const float* __restrict__ xl2, const float* __restrict__ xr2,
    const float* __restrict__ We2, const float* __restrict__ att2,
    const float* __restrict__ bias2,
    const float* __restrict__ Wh1, const float* __restrict__ bh1,
    const float* __restrict__ Wh2, const float* __restrict__ bh2,
    float* __restrict__ out, int N)
{
    int wid = (blockIdx.x * blockDim.x + threadIdx.x) >> 6;
    int lane = threadIdx.x & 63;
    if (wid >= N) return;
    int n = wid;
    int g = lane & 15;
    int slot = lane >> 4;

    float av[4], w0[4], w1[4], xr[4];
    ld4(av, att2 + 4 * g);
    ld4(w0, We2 + 4 * g);
    ld4(w1, We2 + 64 + 4 * g);
    ld4(xr, xr2 + (size_t)n * 64 + 4 * g);

    int s = off[n], e = off[n + 1];
    float m = -3.0e38f, dsum = 0.f;
    float acc[4] = {0, 0, 0, 0};

#pragma unroll 2
    for (int p0 = s; p0 < e; p0 += 4) {
        int p = p0 + slot;
        bool valid = (p < e);
        int4 ed = csr_edge[valid ? p : p0];
        int src = ed.x;
        float eax = __int_as_float(ed.y), eay = __int_as_float(ed.z);
        float xl[4];
        ld4(xl, xl2 + (size_t)src * 64 + 4 * g);

        float pv = 0.f;
#pragma unroll
        for (int i = 0; i < 4; ++i) {
            float gg = xl[i] + xr[i] + fmaf(eax, w0[i], eay * w1[i]);
            gg = fmaxf(gg, NEG_SLOPE * gg);
            pv = fmaf(gg, av[i], pv);
        }
        pv += __shfl_xor(pv, 1);
        pv += __shfl_xor(pv, 2);
        pv += __shfl_xor(pv, 4);
        pv += __shfl_xor(pv, 8);
        float l = valid ? pv : -3.0e38f;
        float bm = fmaxf(l, __shfl_xor(l, 16)); bm = fmaxf(bm, __shfl_xor(bm, 32));
        float nm = fmaxf(m, bm);
        float sc = __expf(m - nm);
        float ev = __expf(l - nm);
        dsum = fmaf(dsum, sc, ev);
#pragma unroll
        for (int i = 0; i < 4; ++i) acc[i] = fmaf(acc[i], sc, ev * xl[i]);
        m = nm;
    }

#pragma unroll
    for (int i = 0; i < 4; ++i) {
        acc[i] += __shfl_xor(acc[i], 16);
        acc[i] += __shfl_xor(acc[i], 32);
    }
    dsum += __shfl_xor(dsum, 16);
    dsum += __shfl_xor(dsum, 32);

    float b2[4];
    ld4(b2, bias2 + 4 * g);
    float r = 1.f / (dsum + 1e-16f);
    float h2[4];
#pragma unroll
    for (int i = 0; i < 4; ++i) h2[i] = fmaxf(fmaf(acc[i], r, b2[i]), 0.f);

    // MLP head: t_j = relu(sum_l h2[l]*Wh1[l][j] + bh1[j]); out = t . Wh2 + bh2
    float t = bh1[lane];
#pragma unroll
    for (int gp = 0; gp < 16; ++gp) {
        t = fmaf(__shfl(h2[0], gp), Wh1[(4 * gp + 0) * 64 + lane], t);
        t = fmaf(__shfl(h2[1], gp), Wh1[(4 * gp + 1) * 64 + lane], t);
        t = fmaf(__shfl(h2[2], gp), Wh1[(4 * gp + 2) * 64 + lane], t);
        t = fmaf(__shfl(h2[3], gp), Wh1[(4 * gp + 3) * 64 + lane], t);
    }
    t = fmaxf(t, 0.f);
    float prt = t * Wh2[lane];
#pragma unroll
    for (int o = 32; o; o >>= 1) prt += __shfl_xor(prt, o);
    if (lane == 0) out[n] = prt + bh2[0];
}

// ---------------------------------------------------------------------------
extern "C" void kernel_launch(void* const* d_in, const int* in_sizes, int n_in,
                              void* d_out, int out_size, void* d_ws, size_t ws_size,
                              hipStream_t stream) {
    const float* x    = (const float*)d_in[0];
    const int*   ei   = (const int*)d_in[1];
    const float* ea   = (const float*)d_in[2];
    const float* Wl1  = (const float*)d_in[3];
    const float* bl1  = (const float*)d_in[4];
    const float* Wr1  = (const float*)d_in[5];
    const float* br1  = (const float*)d_in[6];
    const float* We1  = (const float*)d_in[7];
    const float* att1 = (const float*)d_in[8];
    const float* bias1= (const float*)d_in[9];
    const float* Wl2  = (const float*)d_in[10];
    const float* bl2  = (const float*)d_in[11];
    const float* Wr2  = (const float*)d_in[12];
    const float* br2  = (const float*)d_in[13];
    const float* We2  = (const float*)d_in[14];
    const float* att2 = (const float*)d_in[15];
    const float* bias2= (const float*)d_in[16];
    const float* Wh1  = (const float*)d_in[17];
    const float* bh1  = (const float*)d_in[18];
    const float* Wh2  = (const float*)d_in[19];
    const float* bh2  = (const float*)d_in[20];

    int N = in_sizes[0] / 6;
    int E = in_sizes[1] / 2;
    const int* srcv = ei;
    const int* dstv = ei + E;

    // workspace layout
    char* w = (char*)d_ws;
    auto align256 = [](size_t v) { return (v + 255) & ~(size_t)255; };
    size_t szN64 = align256((size_t)N * 64 * sizeof(float));
    float* xl0t = (float*)(w);                    // layer1 head0 source table
    float* xl1t = (float*)(w + szN64);            // layer1 head1 source table
    float* h1   = (float*)(w + 2 * szN64);        // [N,128]
    float* xl2  = (float*)(w);                    // reuse after c1
    float* xr2  = (float*)(w + szN64);            // reuse after c1

    char* ip = w + 2 * szN64 + align256((size_t)N * 128 * sizeof(float));
    int* deg = (int*)ip;  ip += align256((size_t)N * 4);
    int* off = (int*)ip;  ip += align256((size_t)(N + 1) * 4);
    int* pos = (int*)ip;  ip += align256((size_t)N * 4);
    int B = (N + 511) / 512;
    int* bsum  = (int*)ip; ip += align256((size_t)B * 4);
    int* bpref = (int*)ip; ip += align256((size_t)B * 4);
    int4* csr_edge = (int4*)ip;

    zero_int_kernel<<<(N + 255) / 256, 256, 0, stream>>>(deg, N);
    a1_kernel<<<((size_t)N * 64 + 255) / 256, 256, 0, stream>>>(
        x, Wl1, bl1, xl0t, xl1t, N);
    hist_kernel<<<(E + 255) / 256, 256, 0, stream>>>(dstv, deg, E);
    scan1_kernel<<<B, 256, 0, stream>>>(deg, bsum, N);
    scan2_kernel<<<1, 256, 0, stream>>>(bsum, bpref, off, B, N);
    scan3_kernel<<<B, 256, 0, stream>>>(deg, bpref, off, pos, N);
    scatter_kernel<<<(E + 255) / 256, 256, 0, stream>>>(
        srcv, dstv, (const float2*)ea, pos, csr_edge, E);
    c1_kernel<<<((size_t)N * 64 + 255) / 256, 256, 0, stream>>>(
        off, csr_edge, xl0t, xl1t, x, Wr1, br1, We1, att1, bias1, h1, N);
    {
        int waves = (N + 7) / 8;
        a2_kernel<<<((size_t)waves * 64 + 255) / 256, 256, 0, stream>>>(
            h1, Wl2, bl2, Wr2, br2, xl2, xr2, N);
    }
    c2_kernel<<<((size_t)N * 64 + 255) / 256, 256, 0, stream>>>(
        off, csr_edge, xl2, xr2, We2, att2, bias2,
        Wh1, bh1, Wh2, bh2, (float*)d_out, N);
}

// Round 3
// 756.533 us; speedup vs baseline: 1.2894x; 1.0262x over previous
//
#include <hip/hip_runtime.h>
#include <hip/hip_bf16.h>

#define NEG_SLOPE 0.2f

__device__ __forceinline__ void ld4(float* d, const float* p) {
    float4 t = *(const float4*)p;
    d[0] = t.x; d[1] = t.y; d[2] = t.z; d[3] = t.w;
}

// ---------------------------------------------------------------------------
// PREP: layer-1 source transform (a1) + dst-degree histogram, fused.
// thread t < N*64 : a1 work for (node, channel). grid-stride over E for hist.
// ---------------------------------------------------------------------------
__global__ void __launch_bounds__(256) prep_kernel(
    const float* __restrict__ x,
    const float* __restrict__ Wl1, const float* __restrict__ bl1,
    float* __restrict__ xl0t, float* __restrict__ xl1t,
    const int* __restrict__ dstv, int* __restrict__ deg,
    int N, int E)
{
    int gt = blockIdx.x * blockDim.x + threadIdx.x;
    int total = blockDim.x * gridDim.x;
    // histogram part (grid-stride)
    for (int e = gt; e < E; e += total) atomicAdd(&deg[dstv[e]], 1);
    // a1 part
    int n = gt >> 6, c = gt & 63;
    if (n >= N) return;
    const float* xrow = x + (size_t)n * 6;
    float l0 = bl1[c], l1 = bl1[64 + c];
#pragma unroll
    for (int f = 0; f < 6; ++f) {
        float xv = xrow[f];
        l0 = fmaf(xv, Wl1[f * 128 + c], l0);
        l1 = fmaf(xv, Wl1[f * 128 + 64 + c], l1);
    }
    xl0t[(size_t)n * 64 + c] = l0;
    xl1t[(size_t)n * 64 + c] = l1;
}

// ---------------------------------------------------------------------------
// CSR build: scan + scatter
// ---------------------------------------------------------------------------
__global__ void scan1_kernel(const int* __restrict__ deg, int* __restrict__ bsum, int N) {
    __shared__ int red[256];
    int b = blockIdx.x, t = threadIdx.x;
    int i0 = b * 512 + t, i1 = i0 + 256;
    int v = 0;
    if (i0 < N) v += deg[i0];
    if (i1 < N) v += deg[i1];
    red[t] = v;
    __syncthreads();
    for (int s = 128; s > 0; s >>= 1) {
        if (t < s) red[t] += red[t + s];
        __syncthreads();
    }
    if (t == 0) bsum[b] = red[0];
}

__global__ void scan2_kernel(const int* __restrict__ bsum, int* __restrict__ bpref,
                             int* __restrict__ off, int B, int N) {
    __shared__ int lds[1024];
    int t = threadIdx.x;
    for (int i = t; i < B; i += blockDim.x) lds[i] = bsum[i];
    __syncthreads();
    if (t == 0) {
        int run = 0;
        for (int i = 0; i < B; ++i) { int v = lds[i]; lds[i] = run; run += v; }
        off[N] = run;
    }
    __syncthreads();
    for (int i = t; i < B; i += blockDim.x) bpref[i] = lds[i];
}

__global__ void scan3_kernel(const int* __restrict__ deg, const int* __restrict__ bpref,
                             int* __restrict__ off, int* __restrict__ pos, int N) {
    __shared__ int lds[512];
    int b = blockIdx.x, t = threadIdx.x;
    int base = b * 512;
    for (int i = t; i < 512; i += 256) {
        int g = base + i;
        lds[i] = (g < N) ? deg[g] : 0;
    }
    __syncthreads();
    if (t == 0) {
        int run = bpref[b];
        for (int i = 0; i < 512; ++i) { int v = lds[i]; lds[i] = run; run += v; }
    }
    __syncthreads();
    for (int i = t; i < 512; i += 256) {
        int g = base + i;
        if (g < N) { off[g] = lds[i]; pos[g] = lds[i]; }
    }
}

// one scattered 16B write per edge: {src, ea.x, ea.y, pad}
__global__ void scatter_kernel(const int* __restrict__ srcv, const int* __restrict__ dstv,
                               const float2* __restrict__ ea2, int* __restrict__ pos,
                               int4* __restrict__ csr_edge, int E) {
    int e = blockIdx.x * blockDim.x + threadIdx.x;
    if (e >= E) return;
    int d = dstv[e];
    int p = atomicAdd(&pos[d], 1);
    float2 ea = ea2[e];
    int4 v;
    v.x = srcv[e];
    v.y = __float_as_int(ea.x);
    v.z = __float_as_int(ea.y);
    v.w = 0;
    csr_edge[p] = v;
}

// ---------------------------------------------------------------------------
// C1: layer-1 aggregation. Wave per dst node; 4 edges/iter x 16 lanes/edge,
// each lane owns 4 channels of both heads. No max-subtraction (logits are
// O(1) by construction; softmax is shift-invariant) -> no serial chain.
// ---------------------------------------------------------------------------
__global__ void __launch_bounds__(256) c1_kernel(
    const int* __restrict__ off, const int4* __restrict__ csr_edge,
    const float* __restrict__ xl0t, const float* __restrict__ xl1t,
    const float* __restrict__ x,
    const float* __restrict__ Wr1, const float* __restrict__ br1,
    const float* __restrict__ We1, const float* __restrict__ att1,
    const float* __restrict__ bias1,
    float* __restrict__ h1, int N)
{
    int wid = (blockIdx.x * blockDim.x + threadIdx.x) >> 6;
    int lane = threadIdx.x & 63;
    if (wid >= N) return;
    int n = wid;
    int g = lane & 15;
    int slot = lane >> 4;

    float a0[4], a1[4], w00[4], w01[4], w10[4], w11[4];
    ld4(a0, att1 + 4 * g);
    ld4(a1, att1 + 64 + 4 * g);
    ld4(w00, We1 + 4 * g);
    ld4(w01, We1 + 64 + 4 * g);
    ld4(w10, We1 + 128 + 4 * g);
    ld4(w11, We1 + 192 + 4 * g);

    // xr inline: xr = x[n] @ Wr1 + br1 (6-dim input)
    float xr0[4], xr1[4];
    ld4(xr0, br1 + 4 * g);
    ld4(xr1, br1 + 64 + 4 * g);
    {
        const float* xrow = x + (size_t)n * 6;
#pragma unroll
        for (int f = 0; f < 6; ++f) {
            float xv = xrow[f];
            float wa[4], wb[4];
            ld4(wa, Wr1 + f * 128 + 4 * g);
            ld4(wb, Wr1 + f * 128 + 64 + 4 * g);
#pragma unroll
            for (int i = 0; i < 4; ++i) {
                xr0[i] = fmaf(xv, wa[i], xr0[i]);
                xr1[i] = fmaf(xv, wb[i], xr1[i]);
            }
        }
    }

    int s = off[n], e = off[n + 1];
    float d0 = 0.f, d1 = 0.f;
    float acc0[4] = {0, 0, 0, 0}, acc1[4] = {0, 0, 0, 0};

#pragma unroll 2
    for (int p0 = s; p0 < e; p0 += 4) {
        int p = p0 + slot;
        bool valid = (p < e);
        int4 ed = csr_edge[valid ? p : p0];
        int src = ed.x;
        float eax = __int_as_float(ed.y), eay = __int_as_float(ed.z);
        float xl0[4], xl1[4];
        ld4(xl0, xl0t + (size_t)src * 64 + 4 * g);
        ld4(xl1, xl1t + (size_t)src * 64 + 4 * g);

        float p0v = 0.f, p1v = 0.f;
#pragma unroll
        for (int i = 0; i < 4; ++i) {
            float g0 = xl0[i] + xr0[i] + fmaf(eax, w00[i], eay * w10[i]);
            float g1 = xl1[i] + xr1[i] + fmaf(eax, w01[i], eay * w11[i]);
            g0 = fmaxf(g0, NEG_SLOPE * g0);
            g1 = fmaxf(g1, NEG_SLOPE * g1);
            p0v = fmaf(g0, a0[i], p0v);
            p1v = fmaf(g1, a1[i], p1v);
        }
        p0v += __shfl_xor(p0v, 1);  p1v += __shfl_xor(p1v, 1);
        p0v += __shfl_xor(p0v, 2);  p1v += __shfl_xor(p1v, 2);
        p0v += __shfl_xor(p0v, 4);  p1v += __shfl_xor(p1v, 4);
        p0v += __shfl_xor(p0v, 8);  p1v += __shfl_xor(p1v, 8);
        float e0 = valid ? __expf(p0v) : 0.f;
        float e1 = valid ? __expf(p1v) : 0.f;
        d0 += e0;
        d1 += e1;
#pragma unroll
        for (int i = 0; i < 4; ++i) {
            acc0[i] = fmaf(e0, xl0[i], acc0[i]);
            acc1[i] = fmaf(e1, xl1[i], acc1[i]);
        }
    }

#pragma unroll
    for (int i = 0; i < 4; ++i) {
        acc0[i] += __shfl_xor(acc0[i], 16); acc0[i] += __shfl_xor(acc0[i], 32);
        acc1[i] += __shfl_xor(acc1[i], 16); acc1[i] += __shfl_xor(acc1[i], 32);
    }
    d0 += __shfl_xor(d0, 16); d0 += __shfl_xor(d0, 32);
    d1 += __shfl_xor(d1, 16); d1 += __shfl_xor(d1, 32);

    if (slot == 0) {
        float b0[4], b1[4];
        ld4(b0, bias1 + 4 * g);
        ld4(b1, bias1 + 64 + 4 * g);
        float r0 = 1.f / (d0 + 1e-16f), r1 = 1.f / (d1 + 1e-16f);
        float4 o0, o1;
        o0.x = fmaxf(fmaf(acc0[0], r0, b0[0]), 0.f);
        o0.y = fmaxf(fmaf(acc0[1], r0, b0[1]), 0.f);
        o0.z = fmaxf(fmaf(acc0[2], r0, b0[2]), 0.f);
        o0.w = fmaxf(fmaf(acc0[3], r0, b0[3]), 0.f);
        o1.x = fmaxf(fmaf(acc1[0], r1, b1[0]), 0.f);
        o1.y = fmaxf(fmaf(acc1[1], r1, b1[1]), 0.f);
        o1.z = fmaxf(fmaf(acc1[2], r1, b1[2]), 0.f);
        o1.w = fmaxf(fmaf(acc1[3], r1, b1[3]), 0.f);
        *(float4*)(h1 + (size_t)n * 128 + 4 * g) = o0;
        *(float4*)(h1 + (size_t)n * 128 + 64 + 4 * g) = o1;
    }
}

// ---------------------------------------------------------------------------
// A2: layer-2 node transforms. h1:[N,128] @ Wl2/Wr2:[128,64] (+bias)
// ---------------------------------------------------------------------------
__global__ void __launch_bounds__(256) a2_kernel(
    const float* __restrict__ h1,
    const float* __restrict__ Wl2, const float* __restrict__ bl2,
    const float* __restrict__ Wr2, const float* __restrict__ br2,
    float* __restrict__ xl2, float* __restrict__ xr2, int N)
{
    int wid = (blockIdx.x * blockDim.x + threadIdx.x) >> 6;
    int lane = threadIdx.x & 63;
    int n0 = wid * 8;
    if (n0 >= N) return;

    float hl[8], hh[8], aL[8], aR[8];
#pragma unroll
    for (int j = 0; j < 8; ++j) {
        int n = n0 + j;
        bool v = (n < N);
        hl[j] = v ? h1[(size_t)n * 128 + lane] : 0.f;
        hh[j] = v ? h1[(size_t)n * 128 + 64 + lane] : 0.f;
        aL[j] = bl2[lane];
        aR[j] = br2[lane];
    }
    for (int k = 0; k < 64; ++k) {
        float wl = Wl2[k * 64 + lane];
        float wr = Wr2[k * 64 + lane];
#pragma unroll
        for (int j = 0; j < 8; ++j) {
            float hv = __shfl(hl[j], k);
            aL[j] = fmaf(hv, wl, aL[j]);
            aR[j] = fmaf(hv, wr, aR[j]);
        }
    }
    for (int k = 0; k < 64; ++k) {
        float wl = Wl2[(64 + k) * 64 + lane];
        float wr = Wr2[(64 + k) * 64 + lane];
#pragma unroll
        for (int j = 0; j < 8; ++j) {
            float hv = __shfl(hh[j], k);
            aL[j] = fmaf(hv, wl, aL[j]);
            aR[j] = fmaf(hv, wr, aR[j]);
        }
    }
#pragma unroll
    for (int j = 0; j < 8; ++j) {
        int n = n0 + j;
        if (n < N) {
            xl2[(size_t)n * 64 + lane] = aL[j];
            xr2[(size_t)n * 64 + lane] = aR[j];
        }
    }
}

// ---------------------------------------------------------------------------
// C2: layer-2 aggregation + fused MLP head. No max-subtraction.
// ---------------------------------------------------------------------------
__global__ void __launch_bounds__(256) c2_kernel(
    const int* __restrict__ off, const int4* __restrict__ csr_edge,
    const float* __restrict__ xl2, const float* __restrict__ xr2,
    const float* __restrict__ We2, const float* __restrict__ att2,
    const float* __restrict__ bias2,
    const float* __restrict__ Wh1, const float* __restrict__ bh1,
    const float* __restrict__ Wh2, const float* __restrict__ bh2,
    float* __restrict__ out, int N)
{
    int wid = (blockIdx.x * blockDim.x + threadIdx.x) >> 6;
    int lane = threadIdx.x & 63;
    if (wid >= N) return;
    int n = wid;
    int g = lane & 15;
    int slot = lane >> 4;

    float av[4], w0[4], w1[4], xr[4];
    ld4(av, att2 + 4 * g);
    ld4(w0, We2 + 4 * g);
    ld4(w1, We2 + 64 + 4 * g);
    ld4(xr, xr2 + (size_t)n * 64 + 4 * g);

    int s = off[n], e = off[n + 1];
    float dsum = 0.f;
    float acc[4] = {0, 0, 0, 0};

#pragma unroll 2
    for (int p0 = s; p0 < e; p0 += 4) {
        int p = p0 + slot;
        bool valid = (p < e);
        int4 ed = csr_edge[valid ? p : p0];
        int src = ed.x;
        float eax = __int_as_float(ed.y), eay = __int_as_float(ed.z);
        float xl[4];
        ld4(xl, xl2 + (size_t)src * 64 + 4 * g);

        float pv = 0.f;
#pragma unroll
        for (int i = 0; i < 4; ++i) {
            float gg = xl[i] + xr[i] + fmaf(eax, w0[i], eay * w1[i]);
            gg = fmaxf(gg, NEG_SLOPE * gg);
            pv = fmaf(gg, av[i], pv);
        }
        pv += __shfl_xor(pv, 1);
        pv += __shfl_xor(pv, 2);
        pv += __shfl_xor(pv, 4);
        pv += __shfl_xor(pv, 8);
        float ev = valid ? __expf(pv) : 0.f;
        dsum += ev;
#pragma unroll
        for (int i = 0; i < 4; ++i) acc[i] = fmaf(ev, xl[i], acc[i]);
    }

#pragma unroll
    for (int i = 0; i < 4; ++i) {
        acc[i] += __shfl_xor(acc[i], 16);
        acc[i] += __shfl_xor(acc[i], 32);
    }
    dsum += __shfl_xor(dsum, 16);
    dsum += __shfl_xor(dsum, 32);

    float b2[4];
    ld4(b2, bias2 + 4 * g);
    float r = 1.f / (dsum + 1e-16f);
    float h2[4];
#pragma unroll
    for (int i = 0; i < 4; ++i) h2[i] = fmaxf(fmaf(acc[i], r, b2[i]), 0.f);

    // MLP head
    float t = bh1[lane];
#pragma unroll
    for (int gp = 0; gp < 16; ++gp) {
        t = fmaf(__shfl(h2[0], gp), Wh1[(4 * gp + 0) * 64 + lane], t);
        t = fmaf(__shfl(h2[1], gp), Wh1[(4 * gp + 1) * 64 + lane], t);
        t = fmaf(__shfl(h2[2], gp), Wh1[(4 * gp + 2) * 64 + lane], t);
        t = fmaf(__shfl(h2[3], gp), Wh1[(4 * gp + 3) * 64 + lane], t);
    }
    t = fmaxf(t, 0.f);
    float prt = t * Wh2[lane];
#pragma unroll
    for (int o = 32; o; o >>= 1) prt += __shfl_xor(prt, o);
    if (lane == 0) out[n] = prt + bh2[0];
}

// ---------------------------------------------------------------------------
extern "C" void kernel_launch(void* const* d_in, const int* in_sizes, int n_in,
                              void* d_out, int out_size, void* d_ws, size_t ws_size,
                              hipStream_t stream) {
    const float* x    = (const float*)d_in[0];
    const int*   ei   = (const int*)d_in[1];
    const float* ea   = (const float*)d_in[2];
    const float* Wl1  = (const float*)d_in[3];
    const float* bl1  = (const float*)d_in[4];
    const float* Wr1  = (const float*)d_in[5];
    const float* br1  = (const float*)d_in[6];
    const float* We1  = (const float*)d_in[7];
    const float* att1 = (const float*)d_in[8];
    const float* bias1= (const float*)d_in[9];
    const float* Wl2  = (const float*)d_in[10];
    const float* bl2  = (const float*)d_in[11];
    const float* Wr2  = (const float*)d_in[12];
    const float* br2  = (const float*)d_in[13];
    const float* We2  = (const float*)d_in[14];
    const float* att2 = (const float*)d_in[15];
    const float* bias2= (const float*)d_in[16];
    const float* Wh1  = (const float*)d_in[17];
    const float* bh1  = (const float*)d_in[18];
    const float* Wh2  = (const float*)d_in[19];
    const float* bh2  = (const float*)d_in[20];

    int N = in_sizes[0] / 6;
    int E = in_sizes[1] / 2;
    const int* srcv = ei;
    const int* dstv = ei + E;

    // workspace layout
    char* w = (char*)d_ws;
    auto align256 = [](size_t v) { return (v + 255) & ~(size_t)255; };
    size_t szN64 = align256((size_t)N * 64 * sizeof(float));
    float* xl0t = (float*)(w);
    float* xl1t = (float*)(w + szN64);
    float* h1   = (float*)(w + 2 * szN64);
    float* xl2  = (float*)(w);                    // reuse after c1
    float* xr2  = (float*)(w + szN64);            // reuse after c1

    char* ip = w + 2 * szN64 + align256((size_t)N * 128 * sizeof(float));
    int* deg = (int*)ip;  ip += align256((size_t)N * 4);
    int* off = (int*)ip;  ip += align256((size_t)(N + 1) * 4);
    int* pos = (int*)ip;  ip += align256((size_t)N * 4);
    int B = (N + 511) / 512;
    int* bsum  = (int*)ip; ip += align256((size_t)B * 4);
    int* bpref = (int*)ip; ip += align256((size_t)B * 4);
    int4* csr_edge = (int4*)ip;

    hipMemsetAsync(deg, 0, (size_t)N * sizeof(int), stream);
    prep_kernel<<<((size_t)N * 64 + 255) / 256, 256, 0, stream>>>(
        x, Wl1, bl1, xl0t, xl1t, dstv, deg, N, E);
    scan1_kernel<<<B, 256, 0, stream>>>(deg, bsum, N);
    scan2_kernel<<<1, 256, 0, stream>>>(bsum, bpref, off, B, N);
    scan3_kernel<<<B, 256, 0, stream>>>(deg, bpref, off, pos, N);
    scatter_kernel<<<(E + 255) / 256, 256, 0, stream>>>(
        srcv, dstv, (const float2*)ea, pos, csr_edge, E);
    c1_kernel<<<((size_t)N * 64 + 255) / 256, 256, 0, stream>>>(
        off, csr_edge, xl0t, xl1t, x, Wr1, br1, We1, att1, bias1, h1, N);
    {
        int waves = (N + 7) / 8;
        a2_kernel<<<((size_t)waves * 64 + 255) / 256, 256, 0, stream>>>(
            h1, Wl2, bl2, Wr2, br2, xl2, xr2, N);
    }
    c2_kernel<<<((size_t)N * 64 + 255) / 256, 256, 0, stream>>>(
        off, csr_edge, xl2, xr2, We2, att2, bias2,
        Wh1, bh1, Wh2, bh2, (float*)d_out, N);
}

// Round 4
// 724.942 us; speedup vs baseline: 1.3455x; 1.0436x over previous
//
#include <hip/hip_runtime.h>
#include <hip/hip_bf16.h>

#define NEG_SLOPE 0.2f

typedef _Float16 half8 __attribute__((ext_vector_type(8)));
typedef _Float16 half4 __attribute__((ext_vector_type(4)));
typedef _Float16 half2t __attribute__((ext_vector_type(2)));

__device__ __forceinline__ void ld4(float* d, const float* p) {
    float4 t = *(const float4*)p;
    d[0] = t.x; d[1] = t.y; d[2] = t.z; d[3] = t.w;
}

__device__ __forceinline__ unsigned pack2h(float a, float b) {
    union { half2t h; unsigned u; } pk;
    pk.h[0] = (_Float16)a; pk.h[1] = (_Float16)b;
    return pk.u;
}

// ---------------------------------------------------------------------------
// PREP: layer-1 source transform -> fp16 interleaved table + dst histogram.
// xlh layout: node n, channel c, head h at  n*128 + 2c + h   (fp16)
// ---------------------------------------------------------------------------
__global__ void __launch_bounds__(256) prep_kernel(
    const float* __restrict__ x,
    const float* __restrict__ Wl1, const float* __restrict__ bl1,
    _Float16* __restrict__ xlh,
    const int* __restrict__ dstv, int* __restrict__ deg,
    int N, int E)
{
    int gt = blockIdx.x * blockDim.x + threadIdx.x;
    int total = blockDim.x * gridDim.x;
    for (int e = gt; e < E; e += total) atomicAdd(&deg[dstv[e]], 1);
    int n = gt >> 6, c = gt & 63;
    if (n >= N) return;
    const float* xrow = x + (size_t)n * 6;
    float l0 = bl1[c], l1 = bl1[64 + c];
#pragma unroll
    for (int f = 0; f < 6; ++f) {
        float xv = xrow[f];
        l0 = fmaf(xv, Wl1[f * 128 + c], l0);
        l1 = fmaf(xv, Wl1[f * 128 + 64 + c], l1);
    }
    *(unsigned*)(xlh + (size_t)n * 128 + 2 * c) = pack2h(l0, l1);
}

// ---------------------------------------------------------------------------
// CSR build: scan + scatter (8B packed edges)
// ---------------------------------------------------------------------------
__global__ void scan1_kernel(const int* __restrict__ deg, int* __restrict__ bsum, int N) {
    __shared__ int red[256];
    int b = blockIdx.x, t = threadIdx.x;
    int i0 = b * 512 + t, i1 = i0 + 256;
    int v = 0;
    if (i0 < N) v += deg[i0];
    if (i1 < N) v += deg[i1];
    red[t] = v;
    __syncthreads();
    for (int s = 128; s > 0; s >>= 1) {
        if (t < s) red[t] += red[t + s];
        __syncthreads();
    }
    if (t == 0) bsum[b] = red[0];
}

__global__ void scan2_kernel(const int* __restrict__ bsum, int* __restrict__ bpref,
                             int* __restrict__ off, int B, int N) {
    __shared__ int lds[1024];
    int t = threadIdx.x;
    for (int i = t; i < B; i += blockDim.x) lds[i] = bsum[i];
    __syncthreads();
    if (t == 0) {
        int run = 0;
        for (int i = 0; i < B; ++i) { int v = lds[i]; lds[i] = run; run += v; }
        off[N] = run;
    }
    __syncthreads();
    for (int i = t; i < B; i += blockDim.x) bpref[i] = lds[i];
}

__global__ void scan3_kernel(const int* __restrict__ deg, const int* __restrict__ bpref,
                             int* __restrict__ off, int* __restrict__ pos, int N) {
    __shared__ int lds[512];
    int b = blockIdx.x, t = threadIdx.x;
    int base = b * 512;
    for (int i = t; i < 512; i += 256) {
        int g = base + i;
        lds[i] = (g < N) ? deg[g] : 0;
    }
    __syncthreads();
    if (t == 0) {
        int run = bpref[b];
        for (int i = 0; i < 512; ++i) { int v = lds[i]; lds[i] = run; run += v; }
    }
    __syncthreads();
    for (int i = t; i < 512; i += 256) {
        int g = base + i;
        if (g < N) { off[g] = lds[i]; pos[g] = lds[i]; }
    }
}

// 8B per edge: {src, half2(ea.x, ea.y)}
__global__ void scatter_kernel(const int* __restrict__ srcv, const int* __restrict__ dstv,
                               const float2* __restrict__ ea2, int* __restrict__ pos,
                               int2* __restrict__ csr_edge, int E) {
    int e = blockIdx.x * blockDim.x + threadIdx.x;
    if (e >= E) return;
    int d = dstv[e];
    int p = atomicAdd(&pos[d], 1);
    float2 ea = ea2[e];
    int2 v;
    v.x = srcv[e];
    v.y = (int)pack2h(ea.x, ea.y);
    csr_edge[p] = v;
}

// ---------------------------------------------------------------------------
// C1: layer-1 aggregation. Wave per dst node; 4 edges x 16 lanes/edge.
// Lane g loads 16B of fp16 row = channels 4g..4g+3, both heads.
// ---------------------------------------------------------------------------
__global__ void __launch_bounds__(256) c1_kernel(
    const int* __restrict__ off, const int2* __restrict__ csr_edge,
    const _Float16* __restrict__ xlh,
    const float* __restrict__ x,
    const float* __restrict__ Wr1, const float* __restrict__ br1,
    const float* __restrict__ We1, const float* __restrict__ att1,
    const float* __restrict__ bias1,
    float* __restrict__ h1, int N)
{
    int wid = (blockIdx.x * blockDim.x + threadIdx.x) >> 6;
    int lane = threadIdx.x & 63;
    if (wid >= N) return;
    int n = wid;
    int g = lane & 15;
    int slot = lane >> 4;

    float a0[4], a1[4], w00[4], w01[4], w10[4], w11[4];
    ld4(a0, att1 + 4 * g);
    ld4(a1, att1 + 64 + 4 * g);
    ld4(w00, We1 + 4 * g);
    ld4(w01, We1 + 64 + 4 * g);
    ld4(w10, We1 + 128 + 4 * g);
    ld4(w11, We1 + 192 + 4 * g);

    float xr0[4], xr1[4];
    ld4(xr0, br1 + 4 * g);
    ld4(xr1, br1 + 64 + 4 * g);
    {
        const float* xrow = x + (size_t)n * 6;
#pragma unroll
        for (int f = 0; f < 6; ++f) {
            float xv = xrow[f];
            float wa[4], wb[4];
            ld4(wa, Wr1 + f * 128 + 4 * g);
            ld4(wb, Wr1 + f * 128 + 64 + 4 * g);
#pragma unroll
            for (int i = 0; i < 4; ++i) {
                xr0[i] = fmaf(xv, wa[i], xr0[i]);
                xr1[i] = fmaf(xv, wb[i], xr1[i]);
            }
        }
    }

    int s = off[n], e = off[n + 1];
    float d0 = 0.f, d1 = 0.f;
    float acc0[4] = {0, 0, 0, 0}, acc1[4] = {0, 0, 0, 0};

#pragma unroll 2
    for (int p0 = s; p0 < e; p0 += 4) {
        int p = p0 + slot;
        bool valid = (p < e);
        int2 ed = csr_edge[valid ? p : p0];
        int src = ed.x;
        union { int u; half2t h; } eap; eap.u = ed.y;
        float eax = (float)eap.h[0], eay = (float)eap.h[1];

        half8 hv = *(const half8*)(xlh + (size_t)src * 128 + 8 * g);
        float xl0[4], xl1[4];
#pragma unroll
        for (int i = 0; i < 4; ++i) {
            xl0[i] = (float)hv[2 * i];
            xl1[i] = (float)hv[2 * i + 1];
        }

        float p0v = 0.f, p1v = 0.f;
#pragma unroll
        for (int i = 0; i < 4; ++i) {
            float g0 = xl0[i] + xr0[i] + fmaf(eax, w00[i], eay * w10[i]);
            float g1 = xl1[i] + xr1[i] + fmaf(eax, w01[i], eay * w11[i]);
            g0 = fmaxf(g0, NEG_SLOPE * g0);
            g1 = fmaxf(g1, NEG_SLOPE * g1);
            p0v = fmaf(g0, a0[i], p0v);
            p1v = fmaf(g1, a1[i], p1v);
        }
        p0v += __shfl_xor(p0v, 1);  p1v += __shfl_xor(p1v, 1);
        p0v += __shfl_xor(p0v, 2);  p1v += __shfl_xor(p1v, 2);
        p0v += __shfl_xor(p0v, 4);  p1v += __shfl_xor(p1v, 4);
        p0v += __shfl_xor(p0v, 8);  p1v += __shfl_xor(p1v, 8);
        float e0 = valid ? __expf(p0v) : 0.f;
        float e1 = valid ? __expf(p1v) : 0.f;
        d0 += e0;
        d1 += e1;
#pragma unroll
        for (int i = 0; i < 4; ++i) {
            acc0[i] = fmaf(e0, xl0[i], acc0[i]);
            acc1[i] = fmaf(e1, xl1[i], acc1[i]);
        }
    }

#pragma unroll
    for (int i = 0; i < 4; ++i) {
        acc0[i] += __shfl_xor(acc0[i], 16); acc0[i] += __shfl_xor(acc0[i], 32);
        acc1[i] += __shfl_xor(acc1[i], 16); acc1[i] += __shfl_xor(acc1[i], 32);
    }
    d0 += __shfl_xor(d0, 16); d0 += __shfl_xor(d0, 32);
    d1 += __shfl_xor(d1, 16); d1 += __shfl_xor(d1, 32);

    if (slot == 0) {
        float b0[4], b1[4];
        ld4(b0, bias1 + 4 * g);
        ld4(b1, bias1 + 64 + 4 * g);
        float r0 = 1.f / (d0 + 1e-16f), r1 = 1.f / (d1 + 1e-16f);
        float4 o0, o1;
        o0.x = fmaxf(fmaf(acc0[0], r0, b0[0]), 0.f);
        o0.y = fmaxf(fmaf(acc0[1], r0, b0[1]), 0.f);
        o0.z = fmaxf(fmaf(acc0[2], r0, b0[2]), 0.f);
        o0.w = fmaxf(fmaf(acc0[3], r0, b0[3]), 0.f);
        o1.x = fmaxf(fmaf(acc1[0], r1, b1[0]), 0.f);
        o1.y = fmaxf(fmaf(acc1[1], r1, b1[1]), 0.f);
        o1.z = fmaxf(fmaf(acc1[2], r1, b1[2]), 0.f);
        o1.w = fmaxf(fmaf(acc1[3], r1, b1[3]), 0.f);
        *(float4*)(h1 + (size_t)n * 128 + 4 * g) = o0;
        *(float4*)(h1 + (size_t)n * 128 + 64 + 4 * g) = o1;
    }
}

// ---------------------------------------------------------------------------
// A2: layer-2 node transforms. xl2 -> fp16 table, xr2 stays fp32.
// ---------------------------------------------------------------------------
__global__ void __launch_bounds__(256) a2_kernel(
    const float* __restrict__ h1,
    const float* __restrict__ Wl2, const float* __restrict__ bl2,
    const float* __restrict__ Wr2, const float* __restrict__ br2,
    _Float16* __restrict__ xl2h, float* __restrict__ xr2, int N)
{
    int wid = (blockIdx.x * blockDim.x + threadIdx.x) >> 6;
    int lane = threadIdx.x & 63;
    int n0 = wid * 8;
    if (n0 >= N) return;

    float hl[8], hh[8], aL[8], aR[8];
#pragma unroll
    for (int j = 0; j < 8; ++j) {
        int n = n0 + j;
        bool v = (n < N);
        hl[j] = v ? h1[(size_t)n * 128 + lane] : 0.f;
        hh[j] = v ? h1[(size_t)n * 128 + 64 + lane] : 0.f;
        aL[j] = bl2[lane];
        aR[j] = br2[lane];
    }
    for (int k = 0; k < 64; ++k) {
        float wl = Wl2[k * 64 + lane];
        float wr = Wr2[k * 64 + lane];
#pragma unroll
        for (int j = 0; j < 8; ++j) {
            float hv = __shfl(hl[j], k);
            aL[j] = fmaf(hv, wl, aL[j]);
            aR[j] = fmaf(hv, wr, aR[j]);
        }
    }
    for (int k = 0; k < 64; ++k) {
        float wl = Wl2[(64 + k) * 64 + lane];
        float wr = Wr2[(64 + k) * 64 + lane];
#pragma unroll
        for (int j = 0; j < 8; ++j) {
            float hv = __shfl(hh[j], k);
            aL[j] = fmaf(hv, wl, aL[j]);
            aR[j] = fmaf(hv, wr, aR[j]);
        }
    }
#pragma unroll
    for (int j = 0; j < 8; ++j) {
        int n = n0 + j;
        if (n < N) {
            xl2h[(size_t)n * 64 + lane] = (_Float16)aL[j];
            xr2[(size_t)n * 64 + lane] = aR[j];
        }
    }
}

// ---------------------------------------------------------------------------
// C2: layer-2 aggregation + fused MLP head.
// ---------------------------------------------------------------------------
__global__ void __launch_bounds__(256) c2_kernel(
    const int* __restrict__ off, const int2* __restrict__ csr_edge,
    const _Float16* __restrict__ xl2h, const float* __restrict__ xr2,
    const float* __restrict__ We2, const float* __restrict__ att2,
    const float* __restrict__ bias2,
    const float* __restrict__ Wh1, const float* __restrict__ bh1,
    const float* __restrict__ Wh2, const float* __restrict__ bh2,
    float* __restrict__ out, int N)
{
    int wid = (blockIdx.x * blockDim.x + threadIdx.x) >> 6;
    int lane = threadIdx.x & 63;
    if (wid >= N) return;
    int n = wid;
    int g = lane & 15;
    int slot = lane >> 4;

    float av[4], w0[4], w1[4], xr[4];
    ld4(av, att2 + 4 * g);
    ld4(w0, We2 + 4 * g);
    ld4(w1, We2 + 64 + 4 * g);
    ld4(xr, xr2 + (size_t)n * 64 + 4 * g);

    int s = off[n], e = off[n + 1];
    float dsum = 0.f;
    float acc[4] = {0, 0, 0, 0};

#pragma unroll 2
    for (int p0 = s; p0 < e; p0 += 4) {
        int p = p0 + slot;
        bool valid = (p < e);
        int2 ed = csr_edge[valid ? p : p0];
        int src = ed.x;
        union { int u; half2t h; } eap; eap.u = ed.y;
        float eax = (float)eap.h[0], eay = (float)eap.h[1];

        half4 hv = *(const half4*)(xl2h + (size_t)src * 64 + 4 * g);
        float xl[4];
#pragma unroll
        for (int i = 0; i < 4; ++i) xl[i] = (float)hv[i];

        float pv = 0.f;
#pragma unroll
        for (int i = 0; i < 4; ++i) {
            float gg = xl[i] + xr[i] + fmaf(eax, w0[i], eay * w1[i]);
            gg = fmaxf(gg, NEG_SLOPE * gg);
            pv = fmaf(gg, av[i], pv);
        }
        pv += __shfl_xor(pv, 1);
        pv += __shfl_xor(pv, 2);
        pv += __shfl_xor(pv, 4);
        pv += __shfl_xor(pv, 8);
        float ev = valid ? __expf(pv) : 0.f;
        dsum += ev;
#pragma unroll
        for (int i = 0; i < 4; ++i) acc[i] = fmaf(ev, xl[i], acc[i]);
    }

#pragma unroll
    for (int i = 0; i < 4; ++i) {
        acc[i] += __shfl_xor(acc[i], 16);
        acc[i] += __shfl_xor(acc[i], 32);
    }
    dsum += __shfl_xor(dsum, 16);
    dsum += __shfl_xor(dsum, 32);

    float b2[4];
    ld4(b2, bias2 + 4 * g);
    float r = 1.f / (dsum + 1e-16f);
    float h2[4];
#pragma unroll
    for (int i = 0; i < 4; ++i) h2[i] = fmaxf(fmaf(acc[i], r, b2[i]), 0.f);

    // MLP head
    float t = bh1[lane];
#pragma unroll
    for (int gp = 0; gp < 16; ++gp) {
        t = fmaf(__shfl(h2[0], gp), Wh1[(4 * gp + 0) * 64 + lane], t);
        t = fmaf(__shfl(h2[1], gp), Wh1[(4 * gp + 1) * 64 + lane], t);
        t = fmaf(__shfl(h2[2], gp), Wh1[(4 * gp + 2) * 64 + lane], t);
        t = fmaf(__shfl(h2[3], gp), Wh1[(4 * gp + 3) * 64 + lane], t);
    }
    t = fmaxf(t, 0.f);
    float prt = t * Wh2[lane];
#pragma unroll
    for (int o = 32; o; o >>= 1) prt += __shfl_xor(prt, o);
    if (lane == 0) out[n] = prt + bh2[0];
}

// ---------------------------------------------------------------------------
extern "C" void kernel_launch(void* const* d_in, const int* in_sizes, int n_in,
                              void* d_out, int out_size, void* d_ws, size_t ws_size,
                              hipStream_t stream) {
    const float* x    = (const float*)d_in[0];
    const int*   ei   = (const int*)d_in[1];
    const float* ea   = (const float*)d_in[2];
    const float* Wl1  = (const float*)d_in[3];
    const float* bl1  = (const float*)d_in[4];
    const float* Wr1  = (const float*)d_in[5];
    const float* br1  = (const float*)d_in[6];
    const float* We1  = (const float*)d_in[7];
    const float* att1 = (const float*)d_in[8];
    const float* bias1= (const float*)d_in[9];
    const float* Wl2  = (const float*)d_in[10];
    const float* bl2  = (const float*)d_in[11];
    const float* Wr2  = (const float*)d_in[12];
    const float* br2  = (const float*)d_in[13];
    const float* We2  = (const float*)d_in[14];
    const float* att2 = (const float*)d_in[15];
    const float* bias2= (const float*)d_in[16];
    const float* Wh1  = (const float*)d_in[17];
    const float* bh1  = (const float*)d_in[18];
    const float* Wh2  = (const float*)d_in[19];
    const float* bh2  = (const float*)d_in[20];

    int N = in_sizes[0] / 6;
    int E = in_sizes[1] / 2;
    const int* srcv = ei;
    const int* dstv = ei + E;

    // workspace layout
    char* w = (char*)d_ws;
    auto align256 = [](size_t v) { return (v + 255) & ~(size_t)255; };
    _Float16* xlh = (_Float16*)w;                       // [N][128] fp16
    char* ip = w + align256((size_t)N * 128 * 2);
    float* h1 = (float*)ip;       ip += align256((size_t)N * 128 * 4);
    _Float16* xl2h = (_Float16*)ip; ip += align256((size_t)N * 64 * 2);
    float* xr2 = (float*)ip;      ip += align256((size_t)N * 64 * 4);
    int* deg = (int*)ip;  ip += align256((size_t)N * 4);
    int* off = (int*)ip;  ip += align256((size_t)(N + 1) * 4);
    int* pos = (int*)ip;  ip += align256((size_t)N * 4);
    int B = (N + 511) / 512;
    int* bsum  = (int*)ip; ip += align256((size_t)B * 4);
    int* bpref = (int*)ip; ip += align256((size_t)B * 4);
    int2* csr_edge = (int2*)ip;

    hipMemsetAsync(deg, 0, (size_t)N * sizeof(int), stream);
    prep_kernel<<<((size_t)N * 64 + 255) / 256, 256, 0, stream>>>(
        x, Wl1, bl1, xlh, dstv, deg, N, E);
    scan1_kernel<<<B, 256, 0, stream>>>(deg, bsum, N);
    scan2_kernel<<<1, 256, 0, stream>>>(bsum, bpref, off, B, N);
    scan3_kernel<<<B, 256, 0, stream>>>(deg, bpref, off, pos, N);
    scatter_kernel<<<(E + 255) / 256, 256, 0, stream>>>(
        srcv, dstv, (const float2*)ea, pos, csr_edge, E);
    c1_kernel<<<((size_t)N * 64 + 255) / 256, 256, 0, stream>>>(
        off, csr_edge, xlh, x, Wr1, br1, We1, att1, bias1, h1, N);
    {
        int waves = (N + 7) / 8;
        a2_kernel<<<((size_t)waves * 64 + 255) / 256, 256, 0, stream>>>(
            h1, Wl2, bl2, Wr2, br2, xl2h, xr2, N);
    }
    c2_kernel<<<((size_t)N * 64 + 255) / 256, 256, 0, stream>>>(
        off, csr_edge, xl2h, xr2, We2, att2, bias2,
        Wh1, bh1, Wh2, bh2, (float*)d_out, N);
}

// Round 5
// 688.970 us; speedup vs baseline: 1.4158x; 1.0522x over previous
//
#include <hip/hip_runtime.h>
#include <hip/hip_bf16.h>

#define NEG_SLOPE 0.2f

typedef _Float16 half8 __attribute__((ext_vector_type(8)));
typedef _Float16 half4 __attribute__((ext_vector_type(4)));
typedef _Float16 half2t __attribute__((ext_vector_type(2)));

__device__ __forceinline__ void ld4(float* d, const float* p) {
    float4 t = *(const float4*)p;
    d[0] = t.x; d[1] = t.y; d[2] = t.z; d[3] = t.w;
}

__device__ __forceinline__ unsigned pack2h(float a, float b) {
    union { half2t h; unsigned u; } pk;
    pk.h[0] = (_Float16)a; pk.h[1] = (_Float16)b;
    return pk.u;
}

// ---------------------------------------------------------------------------
// PREP: layer-1 source+target transforms -> fp16 interleaved tables + histogram.
// layout: node n, channel c, head h at  n*128 + 2c + h   (fp16)
// ---------------------------------------------------------------------------
__global__ void __launch_bounds__(256) prep_kernel(
    const float* __restrict__ x,
    const float* __restrict__ Wl1, const float* __restrict__ bl1,
    const float* __restrict__ Wr1, const float* __restrict__ br1,
    _Float16* __restrict__ xlh, _Float16* __restrict__ xrh,
    const int* __restrict__ dstv, int* __restrict__ deg,
    int N, int E)
{
    int gt = blockIdx.x * blockDim.x + threadIdx.x;
    int total = blockDim.x * gridDim.x;
    for (int e = gt; e < E; e += total) atomicAdd(&deg[dstv[e]], 1);
    int n = gt >> 6, c = gt & 63;
    if (n >= N) return;
    const float* xrow = x + (size_t)n * 6;
    float l0 = bl1[c], l1 = bl1[64 + c];
    float r0 = br1[c], r1 = br1[64 + c];
#pragma unroll
    for (int f = 0; f < 6; ++f) {
        float xv = xrow[f];
        l0 = fmaf(xv, Wl1[f * 128 + c], l0);
        l1 = fmaf(xv, Wl1[f * 128 + 64 + c], l1);
        r0 = fmaf(xv, Wr1[f * 128 + c], r0);
        r1 = fmaf(xv, Wr1[f * 128 + 64 + c], r1);
    }
    *(unsigned*)(xlh + (size_t)n * 128 + 2 * c) = pack2h(l0, l1);
    *(unsigned*)(xrh + (size_t)n * 128 + 2 * c) = pack2h(r0, r1);
}

// ---------------------------------------------------------------------------
// CSR build: scan + scatter (8B packed edges)
// ---------------------------------------------------------------------------
__global__ void scan1_kernel(const int* __restrict__ deg, int* __restrict__ bsum, int N) {
    __shared__ int red[256];
    int b = blockIdx.x, t = threadIdx.x;
    int i0 = b * 512 + t, i1 = i0 + 256;
    int v = 0;
    if (i0 < N) v += deg[i0];
    if (i1 < N) v += deg[i1];
    red[t] = v;
    __syncthreads();
    for (int s = 128; s > 0; s >>= 1) {
        if (t < s) red[t] += red[t + s];
        __syncthreads();
    }
    if (t == 0) bsum[b] = red[0];
}

__global__ void scan2_kernel(const int* __restrict__ bsum, int* __restrict__ bpref,
                             int* __restrict__ off, int B, int N) {
    __shared__ int lds[1024];
    int t = threadIdx.x;
    for (int i = t; i < B; i += blockDim.x) lds[i] = bsum[i];
    __syncthreads();
    if (t == 0) {
        int run = 0;
        for (int i = 0; i < B; ++i) { int v = lds[i]; lds[i] = run; run += v; }
        off[N] = run;
    }
    __syncthreads();
    for (int i = t; i < B; i += blockDim.x) bpref[i] = lds[i];
}

__global__ void scan3_kernel(const int* __restrict__ deg, const int* __restrict__ bpref,
                             int* __restrict__ off, int* __restrict__ pos, int N) {
    __shared__ int lds[512];
    int b = blockIdx.x, t = threadIdx.x;
    int base = b * 512;
    for (int i = t; i < 512; i += 256) {
        int g = base + i;
        lds[i] = (g < N) ? deg[g] : 0;
    }
    __syncthreads();
    if (t == 0) {
        int run = bpref[b];
        for (int i = 0; i < 512; ++i) { int v = lds[i]; lds[i] = run; run += v; }
    }
    __syncthreads();
    for (int i = t; i < 512; i += 256) {
        int g = base + i;
        if (g < N) { off[g] = lds[i]; pos[g] = lds[i]; }
    }
}

// 8B per edge: {src, half2(ea.x, ea.y)}
__global__ void scatter_kernel(const int* __restrict__ srcv, const int* __restrict__ dstv,
                               const float2* __restrict__ ea2, int* __restrict__ pos,
                               int2* __restrict__ csr_edge, int E) {
    int e = blockIdx.x * blockDim.x + threadIdx.x;
    if (e >= E) return;
    int d = dstv[e];
    int p = atomicAdd(&pos[d], 1);
    float2 ea = ea2[e];
    int2 v;
    v.x = srcv[e];
    v.y = (int)pack2h(ea.x, ea.y);
    csr_edge[p] = v;
}

// ---------------------------------------------------------------------------
// C1: layer-1 aggregation. Wave per dst node; 8 edges/iter (2 quads x 16
// lanes/edge), independent accumulator sets for ILP. fp16 tables, fp32 acc.
// ---------------------------------------------------------------------------
__global__ void __launch_bounds__(256) c1_kernel(
    const int* __restrict__ off, const int2* __restrict__ csr_edge,
    const _Float16* __restrict__ xlh, const _Float16* __restrict__ xrh,
    const float* __restrict__ We1, const float* __restrict__ att1,
    const float* __restrict__ bias1,
    float* __restrict__ h1, int N)
{
    int wid = (blockIdx.x * blockDim.x + threadIdx.x) >> 6;
    int lane = threadIdx.x & 63;
    if (wid >= N) return;
    int n = wid;
    int g = lane & 15;
    int slot = lane >> 4;

    float a0[4], a1[4], w00[4], w01[4], w10[4], w11[4];
    ld4(a0, att1 + 4 * g);
    ld4(a1, att1 + 64 + 4 * g);
    ld4(w00, We1 + 4 * g);
    ld4(w01, We1 + 64 + 4 * g);
    ld4(w10, We1 + 128 + 4 * g);
    ld4(w11, We1 + 192 + 4 * g);

    // xr from precomputed fp16 table (broadcast across slots)
    float xr0[4], xr1[4];
    {
        half8 xrv = *(const half8*)(xrh + (size_t)n * 128 + 8 * g);
#pragma unroll
        for (int i = 0; i < 4; ++i) {
            xr0[i] = (float)xrv[2 * i];
            xr1[i] = (float)xrv[2 * i + 1];
        }
    }

    int s = off[n], e = off[n + 1];
    float d0A = 0.f, d1A = 0.f, d0B = 0.f, d1B = 0.f;
    float acc0A[4] = {0,0,0,0}, acc1A[4] = {0,0,0,0};
    float acc0B[4] = {0,0,0,0}, acc1B[4] = {0,0,0,0};

    for (int p0 = s; p0 < e; p0 += 8) {
        int pA = p0 + slot;
        int pB = p0 + 4 + slot;
        bool vA = (pA < e), vB = (pB < e);
        int2 edA = csr_edge[vA ? pA : s];
        int2 edB = csr_edge[vB ? pB : s];
        int srcA = edA.x, srcB = edB.x;
        union { int u; half2t h; } eA, eB;
        eA.u = edA.y; eB.u = edB.y;
        float eaxA = (float)eA.h[0], eayA = (float)eA.h[1];
        float eaxB = (float)eB.h[0], eayB = (float)eB.h[1];

        half8 hvA = *(const half8*)(xlh + (size_t)srcA * 128 + 8 * g);
        half8 hvB = *(const half8*)(xlh + (size_t)srcB * 128 + 8 * g);

        float xl0A[4], xl1A[4], xl0B[4], xl1B[4];
#pragma unroll
        for (int i = 0; i < 4; ++i) {
            xl0A[i] = (float)hvA[2 * i];
            xl1A[i] = (float)hvA[2 * i + 1];
            xl0B[i] = (float)hvB[2 * i];
            xl1B[i] = (float)hvB[2 * i + 1];
        }

        float pA0 = 0.f, pA1 = 0.f, pB0 = 0.f, pB1 = 0.f;
#pragma unroll
        for (int i = 0; i < 4; ++i) {
            float gA0 = xl0A[i] + xr0[i] + fmaf(eaxA, w00[i], eayA * w10[i]);
            float gA1 = xl1A[i] + xr1[i] + fmaf(eaxA, w01[i], eayA * w11[i]);
            float gB0 = xl0B[i] + xr0[i] + fmaf(eaxB, w00[i], eayB * w10[i]);
            float gB1 = xl1B[i] + xr1[i] + fmaf(eaxB, w01[i], eayB * w11[i]);
            gA0 = fmaxf(gA0, NEG_SLOPE * gA0);
            gA1 = fmaxf(gA1, NEG_SLOPE * gA1);
            gB0 = fmaxf(gB0, NEG_SLOPE * gB0);
            gB1 = fmaxf(gB1, NEG_SLOPE * gB1);
            pA0 = fmaf(gA0, a0[i], pA0);
            pA1 = fmaf(gA1, a1[i], pA1);
            pB0 = fmaf(gB0, a0[i], pB0);
            pB1 = fmaf(gB1, a1[i], pB1);
        }
        // two independent 4-deep reduction chains
        pA0 += __shfl_xor(pA0, 1);  pA1 += __shfl_xor(pA1, 1);
        pB0 += __shfl_xor(pB0, 1);  pB1 += __shfl_xor(pB1, 1);
        pA0 += __shfl_xor(pA0, 2);  pA1 += __shfl_xor(pA1, 2);
        pB0 += __shfl_xor(pB0, 2);  pB1 += __shfl_xor(pB1, 2);
        pA0 += __shfl_xor(pA0, 4);  pA1 += __shfl_xor(pA1, 4);
        pB0 += __shfl_xor(pB0, 4);  pB1 += __shfl_xor(pB1, 4);
        pA0 += __shfl_xor(pA0, 8);  pA1 += __shfl_xor(pA1, 8);
        pB0 += __shfl_xor(pB0, 8);  pB1 += __shfl_xor(pB1, 8);

        float eA0 = vA ? __expf(pA0) : 0.f;
        float eA1 = vA ? __expf(pA1) : 0.f;
        float eB0 = vB ? __expf(pB0) : 0.f;
        float eB1 = vB ? __expf(pB1) : 0.f;
        d0A += eA0; d1A += eA1;
        d0B += eB0; d1B += eB1;
#pragma unroll
        for (int i = 0; i < 4; ++i) {
            acc0A[i] = fmaf(eA0, xl0A[i], acc0A[i]);
            acc1A[i] = fmaf(eA1, xl1A[i], acc1A[i]);
            acc0B[i] = fmaf(eB0, xl0B[i], acc0B[i]);
            acc1B[i] = fmaf(eB1, xl1B[i], acc1B[i]);
        }
    }

    float d0 = d0A + d0B, d1 = d1A + d1B;
    float acc0[4], acc1[4];
#pragma unroll
    for (int i = 0; i < 4; ++i) {
        acc0[i] = acc0A[i] + acc0B[i];
        acc1[i] = acc1A[i] + acc1B[i];
        acc0[i] += __shfl_xor(acc0[i], 16); acc0[i] += __shfl_xor(acc0[i], 32);
        acc1[i] += __shfl_xor(acc1[i], 16); acc1[i] += __shfl_xor(acc1[i], 32);
    }
    d0 += __shfl_xor(d0, 16); d0 += __shfl_xor(d0, 32);
    d1 += __shfl_xor(d1, 16); d1 += __shfl_xor(d1, 32);

    if (slot == 0) {
        float b0[4], b1[4];
        ld4(b0, bias1 + 4 * g);
        ld4(b1, bias1 + 64 + 4 * g);
        float r0 = 1.f / (d0 + 1e-16f), r1 = 1.f / (d1 + 1e-16f);
        float4 o0, o1;
        o0.x = fmaxf(fmaf(acc0[0], r0, b0[0]), 0.f);
        o0.y = fmaxf(fmaf(acc0[1], r0, b0[1]), 0.f);
        o0.z = fmaxf(fmaf(acc0[2], r0, b0[2]), 0.f);
        o0.w = fmaxf(fmaf(acc0[3], r0, b0[3]), 0.f);
        o1.x = fmaxf(fmaf(acc1[0], r1, b1[0]), 0.f);
        o1.y = fmaxf(fmaf(acc1[1], r1, b1[1]), 0.f);
        o1.z = fmaxf(fmaf(acc1[2], r1, b1[2]), 0.f);
        o1.w = fmaxf(fmaf(acc1[3], r1, b1[3]), 0.f);
        *(float4*)(h1 + (size_t)n * 128 + 4 * g) = o0;
        *(float4*)(h1 + (size_t)n * 128 + 64 + 4 * g) = o1;
    }
}

// ---------------------------------------------------------------------------
// A2: layer-2 node transforms. xl2 -> fp16 table, xr2 stays fp32.
// ---------------------------------------------------------------------------
__global__ void __launch_bounds__(256) a2_kernel(
    const float* __restrict__ h1,
    const float* __restrict__ Wl2, const float* __restrict__ bl2,
    const float* __restrict__ Wr2, const float* __restrict__ br2,
    _Float16* __restrict__ xl2h, float* __restrict__ xr2, int N)
{
    int wid = (blockIdx.x * blockDim.x + threadIdx.x) >> 6;
    int lane = threadIdx.x & 63;
    int n0 = wid * 8;
    if (n0 >= N) return;

    float hl[8], hh[8], aL[8], aR[8];
#pragma unroll
    for (int j = 0; j < 8; ++j) {
        int n = n0 + j;
        bool v = (n < N);
        hl[j] = v ? h1[(size_t)n * 128 + lane] : 0.f;
        hh[j] = v ? h1[(size_t)n * 128 + 64 + lane] : 0.f;
        aL[j] = bl2[lane];
        aR[j] = br2[lane];
    }
    for (int k = 0; k < 64; ++k) {
        float wl = Wl2[k * 64 + lane];
        float wr = Wr2[k * 64 + lane];
#pragma unroll
        for (int j = 0; j < 8; ++j) {
            float hv = __shfl(hl[j], k);
            aL[j] = fmaf(hv, wl, aL[j]);
            aR[j] = fmaf(hv, wr, aR[j]);
        }
    }
    for (int k = 0; k < 64; ++k) {
        float wl = Wl2[(64 + k) * 64 + lane];
        float wr = Wr2[(64 + k) * 64 + lane];
#pragma unroll
        for (int j = 0; j < 8; ++j) {
            float hv = __shfl(hh[j], k);
            aL[j] = fmaf(hv, wl, aL[j]);
            aR[j] = fmaf(hv, wr, aR[j]);
        }
    }
#pragma unroll
    for (int j = 0; j < 8; ++j) {
        int n = n0 + j;
        if (n < N) {
            xl2h[(size_t)n * 64 + lane] = (_Float16)aL[j];
            xr2[(size_t)n * 64 + lane] = aR[j];
        }
    }
}

// ---------------------------------------------------------------------------
// C2: layer-2 aggregation + fused MLP head. 8 edges/iter.
// ---------------------------------------------------------------------------
__global__ void __launch_bounds__(256) c2_kernel(
    const int* __restrict__ off, const int2* __restrict__ csr_edge,
    const _Float16* __restrict__ xl2h, const float* __restrict__ xr2,
    const float* __restrict__ We2, const float* __restrict__ att2,
    const float* __restrict__ bias2,
    const float* __restrict__ Wh1, const float* __restrict__ bh1,
    const float* __restrict__ Wh2, const float* __restrict__ bh2,
    float* __restrict__ out, int N)
{
    int wid = (blockIdx.x * blockDim.x + threadIdx.x) >> 6;
    int lane = threadIdx.x & 63;
    if (wid >= N) return;
    int n = wid;
    int g = lane & 15;
    int slot = lane >> 4;

    float av[4], w0[4], w1[4], xr[4];
    ld4(av, att2 + 4 * g);
    ld4(w0, We2 + 4 * g);
    ld4(w1, We2 + 64 + 4 * g);
    ld4(xr, xr2 + (size_t)n * 64 + 4 * g);

    int s = off[n], e = off[n + 1];
    float dA = 0.f, dB = 0.f;
    float accA[4] = {0,0,0,0}, accB[4] = {0,0,0,0};

    for (int p0 = s; p0 < e; p0 += 8) {
        int pA = p0 + slot;
        int pB = p0 + 4 + slot;
        bool vA = (pA < e), vB = (pB < e);
        int2 edA = csr_edge[vA ? pA : s];
        int2 edB = csr_edge[vB ? pB : s];
        int srcA = edA.x, srcB = edB.x;
        union { int u; half2t h; } eA, eB;
        eA.u = edA.y; eB.u = edB.y;
        float eaxA = (float)eA.h[0], eayA = (float)eA.h[1];
        float eaxB = (float)eB.h[0], eayB = (float)eB.h[1];

        half4 hvA = *(const half4*)(xl2h + (size_t)srcA * 64 + 4 * g);
        half4 hvB = *(const half4*)(xl2h + (size_t)srcB * 64 + 4 * g);
        float xlA[4], xlB[4];
#pragma unroll
        for (int i = 0; i < 4; ++i) {
            xlA[i] = (float)hvA[i];
            xlB[i] = (float)hvB[i];
        }

        float pvA = 0.f, pvB = 0.f;
#pragma unroll
        for (int i = 0; i < 4; ++i) {
            float gA = xlA[i] + xr[i] + fmaf(eaxA, w0[i], eayA * w1[i]);
            float gB = xlB[i] + xr[i] + fmaf(eaxB, w0[i], eayB * w1[i]);
            gA = fmaxf(gA, NEG_SLOPE * gA);
            gB = fmaxf(gB, NEG_SLOPE * gB);
            pvA = fmaf(gA, av[i], pvA);
            pvB = fmaf(gB, av[i], pvB);
        }
        pvA += __shfl_xor(pvA, 1);  pvB += __shfl_xor(pvB, 1);
        pvA += __shfl_xor(pvA, 2);  pvB += __shfl_xor(pvB, 2);
        pvA += __shfl_xor(pvA, 4);  pvB += __shfl_xor(pvB, 4);
        pvA += __shfl_xor(pvA, 8);  pvB += __shfl_xor(pvB, 8);
        float evA = vA ? __expf(pvA) : 0.f;
        float evB = vB ? __expf(pvB) : 0.f;
        dA += evA; dB += evB;
#pragma unroll
        for (int i = 0; i < 4; ++i) {
            accA[i] = fmaf(evA, xlA[i], accA[i]);
            accB[i] = fmaf(evB, xlB[i], accB[i]);
        }
    }

    float dsum = dA + dB;
    float acc[4];
#pragma unroll
    for (int i = 0; i < 4; ++i) {
        acc[i] = accA[i] + accB[i];
        acc[i] += __shfl_xor(acc[i], 16);
        acc[i] += __shfl_xor(acc[i], 32);
    }
    dsum += __shfl_xor(dsum, 16);
    dsum += __shfl_xor(dsum, 32);

    float b2[4];
    ld4(b2, bias2 + 4 * g);
    float r = 1.f / (dsum + 1e-16f);
    float h2[4];
#pragma unroll
    for (int i = 0; i < 4; ++i) h2[i] = fmaxf(fmaf(acc[i], r, b2[i]), 0.f);

    // MLP head
    float t = bh1[lane];
#pragma unroll
    for (int gp = 0; gp < 16; ++gp) {
        t = fmaf(__shfl(h2[0], gp), Wh1[(4 * gp + 0) * 64 + lane], t);
        t = fmaf(__shfl(h2[1], gp), Wh1[(4 * gp + 1) * 64 + lane], t);
        t = fmaf(__shfl(h2[2], gp), Wh1[(4 * gp + 2) * 64 + lane], t);
        t = fmaf(__shfl(h2[3], gp), Wh1[(4 * gp + 3) * 64 + lane], t);
    }
    t = fmaxf(t, 0.f);
    float prt = t * Wh2[lane];
#pragma unroll
    for (int o = 32; o; o >>= 1) prt += __shfl_xor(prt, o);
    if (lane == 0) out[n] = prt + bh2[0];
}

// ---------------------------------------------------------------------------
extern "C" void kernel_launch(void* const* d_in, const int* in_sizes, int n_in,
                              void* d_out, int out_size, void* d_ws, size_t ws_size,
                              hipStream_t stream) {
    const float* x    = (const float*)d_in[0];
    const int*   ei   = (const int*)d_in[1];
    const float* ea   = (const float*)d_in[2];
    const float* Wl1  = (const float*)d_in[3];
    const float* bl1  = (const float*)d_in[4];
    const float* Wr1  = (const float*)d_in[5];
    const float* br1  = (const float*)d_in[6];
    const float* We1  = (const float*)d_in[7];
    const float* att1 = (const float*)d_in[8];
    const float* bias1= (const float*)d_in[9];
    const float* Wl2  = (const float*)d_in[10];
    const float* bl2  = (const float*)d_in[11];
    const float* Wr2  = (const float*)d_in[12];
    const float* br2  = (const float*)d_in[13];
    const float* We2  = (const float*)d_in[14];
    const float* att2 = (const float*)d_in[15];
    const float* bias2= (const float*)d_in[16];
    const float* Wh1  = (const float*)d_in[17];
    const float* bh1  = (const float*)d_in[18];
    const float* Wh2  = (const float*)d_in[19];
    const float* bh2  = (const float*)d_in[20];

    int N = in_sizes[0] / 6;
    int E = in_sizes[1] / 2;
    const int* srcv = ei;
    const int* dstv = ei + E;

    // workspace layout
    char* w = (char*)d_ws;
    auto align256 = [](size_t v) { return (v + 255) & ~(size_t)255; };
    _Float16* xlh = (_Float16*)w;
    char* ip = w + align256((size_t)N * 128 * 2);
    _Float16* xrh = (_Float16*)ip; ip += align256((size_t)N * 128 * 2);
    float* h1 = (float*)ip;        ip += align256((size_t)N * 128 * 4);
    _Float16* xl2h = (_Float16*)ip; ip += align256((size_t)N * 64 * 2);
    float* xr2 = (float*)ip;       ip += align256((size_t)N * 64 * 4);
    int* deg = (int*)ip;  ip += align256((size_t)N * 4);
    int* off = (int*)ip;  ip += align256((size_t)(N + 1) * 4);
    int* pos = (int*)ip;  ip += align256((size_t)N * 4);
    int B = (N + 511) / 512;
    int* bsum  = (int*)ip; ip += align256((size_t)B * 4);
    int* bpref = (int*)ip; ip += align256((size_t)B * 4);
    int2* csr_edge = (int2*)ip;

    hipMemsetAsync(deg, 0, (size_t)N * sizeof(int), stream);
    prep_kernel<<<((size_t)N * 64 + 255) / 256, 256, 0, stream>>>(
        x, Wl1, bl1, Wr1, br1, xlh, xrh, dstv, deg, N, E);
    scan1_kernel<<<B, 256, 0, stream>>>(deg, bsum, N);
    scan2_kernel<<<1, 256, 0, stream>>>(bsum, bpref, off, B, N);
    scan3_kernel<<<B, 256, 0, stream>>>(deg, bpref, off, pos, N);
    scatter_kernel<<<(E + 255) / 256, 256, 0, stream>>>(
        srcv, dstv, (const float2*)ea, pos, csr_edge, E);
    c1_kernel<<<((size_t)N * 64 + 255) / 256, 256, 0, stream>>>(
        off, csr_edge, xlh, xrh, We1, att1, bias1, h1, N);
    {
        int waves = (N + 7) / 8;
        a2_kernel<<<((size_t)waves * 64 + 255) / 256, 256, 0, stream>>>(
            h1, Wl2, bl2, Wr2, br2, xl2h, xr2, N);
    }
    c2_kernel<<<((size_t)N * 64 + 255) / 256, 256, 0, stream>>>(
        off, csr_edge, xl2h, xr2, We2, att2, bias2,
        Wh1, bh1, Wh2, bh2, (float*)d_out, N);
}

// Round 6
// 607.836 us; speedup vs baseline: 1.6048x; 1.1335x over previous
//
#include <hip/hip_runtime.h>
#include <hip/hip_bf16.h>

#define NEG_SLOPE 0.2f

typedef _Float16 half8 __attribute__((ext_vector_type(8)));
typedef _Float16 half4 __attribute__((ext_vector_type(4)));
typedef _Float16 half2t __attribute__((ext_vector_type(2)));

__device__ __forceinline__ void ld4(float* d, const float* p) {
    float4 t = *(const float4*)p;
    d[0] = t.x; d[1] = t.y; d[2] = t.z; d[3] = t.w;
}

__device__ __forceinline__ unsigned pack2h(float a, float b) {
    union { half2t h; unsigned u; } pk;
    pk.h[0] = (_Float16)a; pk.h[1] = (_Float16)b;
    return pk.u;
}

// ---------------------------------------------------------------------------
// PREP: layer-1 source+target transforms -> fp16 interleaved tables + histogram.
// layout: node n, channel c, head h at  n*128 + 2c + h   (fp16)
// ---------------------------------------------------------------------------
__global__ void __launch_bounds__(256) prep_kernel(
    const float* __restrict__ x,
    const float* __restrict__ Wl1, const float* __restrict__ bl1,
    const float* __restrict__ Wr1, const float* __restrict__ br1,
    _Float16* __restrict__ xlh, _Float16* __restrict__ xrh,
    const int* __restrict__ dstv, int* __restrict__ deg,
    int N, int E)
{
    int gt = blockIdx.x * blockDim.x + threadIdx.x;
    int total = blockDim.x * gridDim.x;
    for (int e = gt; e < E; e += total) atomicAdd(&deg[dstv[e]], 1);
    int n = gt >> 6, c = gt & 63;
    if (n >= N) return;
    const float* xrow = x + (size_t)n * 6;
    float l0 = bl1[c], l1 = bl1[64 + c];
    float r0 = br1[c], r1 = br1[64 + c];
#pragma unroll
    for (int f = 0; f < 6; ++f) {
        float xv = xrow[f];
        l0 = fmaf(xv, Wl1[f * 128 + c], l0);
        l1 = fmaf(xv, Wl1[f * 128 + 64 + c], l1);
        r0 = fmaf(xv, Wr1[f * 128 + c], r0);
        r1 = fmaf(xv, Wr1[f * 128 + 64 + c], r1);
    }
    *(unsigned*)(xlh + (size_t)n * 128 + 2 * c) = pack2h(l0, l1);
    *(unsigned*)(xrh + (size_t)n * 128 + 2 * c) = pack2h(r0, r1);
}

// ---------------------------------------------------------------------------
// CSR build: scan + scatter (8B packed edges)
// ---------------------------------------------------------------------------
__global__ void scan1_kernel(const int* __restrict__ deg, int* __restrict__ bsum, int N) {
    __shared__ int red[256];
    int b = blockIdx.x, t = threadIdx.x;
    int i0 = b * 512 + t, i1 = i0 + 256;
    int v = 0;
    if (i0 < N) v += deg[i0];
    if (i1 < N) v += deg[i1];
    red[t] = v;
    __syncthreads();
    for (int s = 128; s > 0; s >>= 1) {
        if (t < s) red[t] += red[t + s];
        __syncthreads();
    }
    if (t == 0) bsum[b] = red[0];
}

__global__ void scan2_kernel(const int* __restrict__ bsum, int* __restrict__ bpref,
                             int* __restrict__ off, int B, int N) {
    __shared__ int lds[1024];
    int t = threadIdx.x;
    for (int i = t; i < B; i += blockDim.x) lds[i] = bsum[i];
    __syncthreads();
    if (t == 0) {
        int run = 0;
        for (int i = 0; i < B; ++i) { int v = lds[i]; lds[i] = run; run += v; }
        off[N] = run;
    }
    __syncthreads();
    for (int i = t; i < B; i += blockDim.x) bpref[i] = lds[i];
}

__global__ void scan3_kernel(const int* __restrict__ deg, const int* __restrict__ bpref,
                             int* __restrict__ off, int* __restrict__ pos, int N) {
    __shared__ int lds[512];
    int b = blockIdx.x, t = threadIdx.x;
    int base = b * 512;
    for (int i = t; i < 512; i += 256) {
        int g = base + i;
        lds[i] = (g < N) ? deg[g] : 0;
    }
    __syncthreads();
    if (t == 0) {
        int run = bpref[b];
        for (int i = 0; i < 512; ++i) { int v = lds[i]; lds[i] = run; run += v; }
    }
    __syncthreads();
    for (int i = t; i < 512; i += 256) {
        int g = base + i;
        if (g < N) { off[g] = lds[i]; pos[g] = lds[i]; }
    }
}

// 8B per edge: {src, half2(ea.x, ea.y)}
__global__ void scatter_kernel(const int* __restrict__ srcv, const int* __restrict__ dstv,
                               const float2* __restrict__ ea2, int* __restrict__ pos,
                               int2* __restrict__ csr_edge, int E) {
    int e = blockIdx.x * blockDim.x + threadIdx.x;
    if (e >= E) return;
    int d = dstv[e];
    int p = atomicAdd(&pos[d], 1);
    float2 ea = ea2[e];
    int2 v;
    v.x = srcv[e];
    v.y = (int)pack2h(ea.x, ea.y);
    csr_edge[p] = v;
}

// ---------------------------------------------------------------------------
// C1: layer-1 aggregation. Wave per dst node; 8 edges/iter (2 quads x 16
// lanes/edge), independent accumulator sets for ILP. fp16 tables, fp32 acc.
// ---------------------------------------------------------------------------
__global__ void __launch_bounds__(256) c1_kernel(
    const int* __restrict__ off, const int2* __restrict__ csr_edge,
    const _Float16* __restrict__ xlh, const _Float16* __restrict__ xrh,
    const float* __restrict__ We1, const float* __restrict__ att1,
    const float* __restrict__ bias1,
    float* __restrict__ h1, int N)
{
    int wid = (blockIdx.x * blockDim.x + threadIdx.x) >> 6;
    int lane = threadIdx.x & 63;
    if (wid >= N) return;
    int n = wid;
    int g = lane & 15;
    int slot = lane >> 4;

    float a0[4], a1[4], w00[4], w01[4], w10[4], w11[4];
    ld4(a0, att1 + 4 * g);
    ld4(a1, att1 + 64 + 4 * g);
    ld4(w00, We1 + 4 * g);
    ld4(w01, We1 + 64 + 4 * g);
    ld4(w10, We1 + 128 + 4 * g);
    ld4(w11, We1 + 192 + 4 * g);

    float xr0[4], xr1[4];
    {
        half8 xrv = *(const half8*)(xrh + (size_t)n * 128 + 8 * g);
#pragma unroll
        for (int i = 0; i < 4; ++i) {
            xr0[i] = (float)xrv[2 * i];
            xr1[i] = (float)xrv[2 * i + 1];
        }
    }

    int s = off[n], e = off[n + 1];
    float d0A = 0.f, d1A = 0.f, d0B = 0.f, d1B = 0.f;
    float acc0A[4] = {0,0,0,0}, acc1A[4] = {0,0,0,0};
    float acc0B[4] = {0,0,0,0}, acc1B[4] = {0,0,0,0};

    for (int p0 = s; p0 < e; p0 += 8) {
        int pA = p0 + slot;
        int pB = p0 + 4 + slot;
        bool vA = (pA < e), vB = (pB < e);
        int2 edA = csr_edge[vA ? pA : s];
        int2 edB = csr_edge[vB ? pB : s];
        int srcA = edA.x, srcB = edB.x;
        union { int u; half2t h; } eA, eB;
        eA.u = edA.y; eB.u = edB.y;
        float eaxA = (float)eA.h[0], eayA = (float)eA.h[1];
        float eaxB = (float)eB.h[0], eayB = (float)eB.h[1];

        half8 hvA = *(const half8*)(xlh + (size_t)srcA * 128 + 8 * g);
        half8 hvB = *(const half8*)(xlh + (size_t)srcB * 128 + 8 * g);

        float xl0A[4], xl1A[4], xl0B[4], xl1B[4];
#pragma unroll
        for (int i = 0; i < 4; ++i) {
            xl0A[i] = (float)hvA[2 * i];
            xl1A[i] = (float)hvA[2 * i + 1];
            xl0B[i] = (float)hvB[2 * i];
            xl1B[i] = (float)hvB[2 * i + 1];
        }

        float pA0 = 0.f, pA1 = 0.f, pB0 = 0.f, pB1 = 0.f;
#pragma unroll
        for (int i = 0; i < 4; ++i) {
            float gA0 = xl0A[i] + xr0[i] + fmaf(eaxA, w00[i], eayA * w10[i]);
            float gA1 = xl1A[i] + xr1[i] + fmaf(eaxA, w01[i], eayA * w11[i]);
            float gB0 = xl0B[i] + xr0[i] + fmaf(eaxB, w00[i], eayB * w10[i]);
            float gB1 = xl1B[i] + xr1[i] + fmaf(eaxB, w01[i], eayB * w11[i]);
            gA0 = fmaxf(gA0, NEG_SLOPE * gA0);
            gA1 = fmaxf(gA1, NEG_SLOPE * gA1);
            gB0 = fmaxf(gB0, NEG_SLOPE * gB0);
            gB1 = fmaxf(gB1, NEG_SLOPE * gB1);
            pA0 = fmaf(gA0, a0[i], pA0);
            pA1 = fmaf(gA1, a1[i], pA1);
            pB0 = fmaf(gB0, a0[i], pB0);
            pB1 = fmaf(gB1, a1[i], pB1);
        }
        pA0 += __shfl_xor(pA0, 1);  pA1 += __shfl_xor(pA1, 1);
        pB0 += __shfl_xor(pB0, 1);  pB1 += __shfl_xor(pB1, 1);
        pA0 += __shfl_xor(pA0, 2);  pA1 += __shfl_xor(pA1, 2);
        pB0 += __shfl_xor(pB0, 2);  pB1 += __shfl_xor(pB1, 2);
        pA0 += __shfl_xor(pA0, 4);  pA1 += __shfl_xor(pA1, 4);
        pB0 += __shfl_xor(pB0, 4);  pB1 += __shfl_xor(pB1, 4);
        pA0 += __shfl_xor(pA0, 8);  pA1 += __shfl_xor(pA1, 8);
        pB0 += __shfl_xor(pB0, 8);  pB1 += __shfl_xor(pB1, 8);

        float eA0 = vA ? __expf(pA0) : 0.f;
        float eA1 = vA ? __expf(pA1) : 0.f;
        float eB0 = vB ? __expf(pB0) : 0.f;
        float eB1 = vB ? __expf(pB1) : 0.f;
        d0A += eA0; d1A += eA1;
        d0B += eB0; d1B += eB1;
#pragma unroll
        for (int i = 0; i < 4; ++i) {
            acc0A[i] = fmaf(eA0, xl0A[i], acc0A[i]);
            acc1A[i] = fmaf(eA1, xl1A[i], acc1A[i]);
            acc0B[i] = fmaf(eB0, xl0B[i], acc0B[i]);
            acc1B[i] = fmaf(eB1, xl1B[i], acc1B[i]);
        }
    }

    float d0 = d0A + d0B, d1 = d1A + d1B;
    float acc0[4], acc1[4];
#pragma unroll
    for (int i = 0; i < 4; ++i) {
        acc0[i] = acc0A[i] + acc0B[i];
        acc1[i] = acc1A[i] + acc1B[i];
        acc0[i] += __shfl_xor(acc0[i], 16); acc0[i] += __shfl_xor(acc0[i], 32);
        acc1[i] += __shfl_xor(acc1[i], 16); acc1[i] += __shfl_xor(acc1[i], 32);
    }
    d0 += __shfl_xor(d0, 16); d0 += __shfl_xor(d0, 32);
    d1 += __shfl_xor(d1, 16); d1 += __shfl_xor(d1, 32);

    if (slot == 0) {
        float b0[4], b1[4];
        ld4(b0, bias1 + 4 * g);
        ld4(b1, bias1 + 64 + 4 * g);
        float r0 = 1.f / (d0 + 1e-16f), r1 = 1.f / (d1 + 1e-16f);
        float4 o0, o1;
        o0.x = fmaxf(fmaf(acc0[0], r0, b0[0]), 0.f);
        o0.y = fmaxf(fmaf(acc0[1], r0, b0[1]), 0.f);
        o0.z = fmaxf(fmaf(acc0[2], r0, b0[2]), 0.f);
        o0.w = fmaxf(fmaf(acc0[3], r0, b0[3]), 0.f);
        o1.x = fmaxf(fmaf(acc1[0], r1, b1[0]), 0.f);
        o1.y = fmaxf(fmaf(acc1[1], r1, b1[1]), 0.f);
        o1.z = fmaxf(fmaf(acc1[2], r1, b1[2]), 0.f);
        o1.w = fmaxf(fmaf(acc1[3], r1, b1[3]), 0.f);
        *(float4*)(h1 + (size_t)n * 128 + 4 * g) = o0;
        *(float4*)(h1 + (size_t)n * 128 + 64 + 4 * g) = o1;
    }
}

// ---------------------------------------------------------------------------
// A2: layer-2 node transforms as an LDS-tiled GEMM (no shuffles).
// Block = 256 threads, 64 nodes. Thread (cslot,jgrp) -> 4 channels x 8 nodes.
// Combined output [xl2 | xr2] = 128 channels; both emitted as fp16 tables.
// ---------------------------------------------------------------------------
__global__ void __launch_bounds__(256) a2_kernel(
    const float* __restrict__ h1,
    const float* __restrict__ Wl2, const float* __restrict__ bl2,
    const float* __restrict__ Wr2, const float* __restrict__ br2,
    _Float16* __restrict__ xl2h, _Float16* __restrict__ xr2h, int N)
{
    __shared__ float hs[64 * 128];   // 32 KB
    int tid = threadIdx.x;
    int n0 = blockIdx.x * 64;

    // stage 64 rows of h1 (zero-pad beyond N)
    for (int i = tid; i < 64 * 32; i += 256) {
        int row = i >> 5;
        int q = i & 31;
        int n = n0 + row;
        float4 v = (n < N) ? *(const float4*)(h1 + (size_t)n * 128 + q * 4)
                           : make_float4(0.f, 0.f, 0.f, 0.f);
        *(float4*)(hs + row * 128 + q * 4) = v;
    }
    __syncthreads();

    int cslot = tid & 31;        // 32 slots x 4 ch = 128 outputs
    int jgrp = tid >> 5;         // 8 groups x 8 nodes
    int c4 = cslot * 4;
    bool isL = (c4 < 64);
    int cc = isL ? c4 : (c4 - 64);
    const float* Wb = (isL ? Wl2 : Wr2) + cc;
    const float* bb = (isL ? bl2 : br2) + cc;
    float4 bias = *(const float4*)bb;

    float acc[8][4];
#pragma unroll
    for (int j = 0; j < 8; ++j) {
        acc[j][0] = bias.x; acc[j][1] = bias.y;
        acc[j][2] = bias.z; acc[j][3] = bias.w;
    }

    const float* hrow = hs + (jgrp * 8) * 128;
#pragma unroll 2
    for (int k4 = 0; k4 < 32; ++k4) {
        float4 w0 = *(const float4*)(Wb + (4 * k4 + 0) * 64);
        float4 w1 = *(const float4*)(Wb + (4 * k4 + 1) * 64);
        float4 w2 = *(const float4*)(Wb + (4 * k4 + 2) * 64);
        float4 w3 = *(const float4*)(Wb + (4 * k4 + 3) * 64);
#pragma unroll
        for (int j = 0; j < 8; ++j) {
            float4 hv = *(const float4*)(hrow + j * 128 + k4 * 4);
            acc[j][0] = fmaf(hv.x, w0.x, acc[j][0]);
            acc[j][1] = fmaf(hv.x, w0.y, acc[j][1]);
            acc[j][2] = fmaf(hv.x, w0.z, acc[j][2]);
            acc[j][3] = fmaf(hv.x, w0.w, acc[j][3]);
            acc[j][0] = fmaf(hv.y, w1.x, acc[j][0]);
            acc[j][1] = fmaf(hv.y, w1.y, acc[j][1]);
            acc[j][2] = fmaf(hv.y, w1.z, acc[j][2]);
            acc[j][3] = fmaf(hv.y, w1.w, acc[j][3]);
            acc[j][0] = fmaf(hv.z, w2.x, acc[j][0]);
            acc[j][1] = fmaf(hv.z, w2.y, acc[j][1]);
            acc[j][2] = fmaf(hv.z, w2.z, acc[j][2]);
            acc[j][3] = fmaf(hv.z, w2.w, acc[j][3]);
            acc[j][0] = fmaf(hv.w, w3.x, acc[j][0]);
            acc[j][1] = fmaf(hv.w, w3.y, acc[j][1]);
            acc[j][2] = fmaf(hv.w, w3.z, acc[j][2]);
            acc[j][3] = fmaf(hv.w, w3.w, acc[j][3]);
        }
    }

    _Float16* outb = isL ? xl2h : xr2h;
#pragma unroll
    for (int j = 0; j < 8; ++j) {
        int n = n0 + jgrp * 8 + j;
        if (n < N) {
            half4 o;
            o[0] = (_Float16)acc[j][0];
            o[1] = (_Float16)acc[j][1];
            o[2] = (_Float16)acc[j][2];
            o[3] = (_Float16)acc[j][3];
            *(half4*)(outb + (size_t)n * 64 + cc) = o;
        }
    }
}

// ---------------------------------------------------------------------------
// C2: layer-2 aggregation + fused MLP head. 8 edges/iter. fp16 xl/xr tables.
// ---------------------------------------------------------------------------
__global__ void __launch_bounds__(256) c2_kernel(
    const int* __restrict__ off, const int2* __restrict__ csr_edge,
    const _Float16* __restrict__ xl2h, const _Float16* __restrict__ xr2h,
    const float* __restrict__ We2, const float* __restrict__ att2,
    const float* __restrict__ bias2,
    const float* __restrict__ Wh1, const float* __restrict__ bh1,
    const float* __restrict__ Wh2, const float* __restrict__ bh2,
    float* __restrict__ out, int N)
{
    int wid = (blockIdx.x * blockDim.x + threadIdx.x) >> 6;
    int lane = threadIdx.x & 63;
    if (wid >= N) return;
    int n = wid;
    int g = lane & 15;
    int slot = lane >> 4;

    float av[4], w0[4], w1[4], xr[4];
    ld4(av, att2 + 4 * g);
    ld4(w0, We2 + 4 * g);
    ld4(w1, We2 + 64 + 4 * g);
    {
        half4 xrv = *(const half4*)(xr2h + (size_t)n * 64 + 4 * g);
#pragma unroll
        for (int i = 0; i < 4; ++i) xr[i] = (float)xrv[i];
    }

    int s = off[n], e = off[n + 1];
    float dA = 0.f, dB = 0.f;
    float accA[4] = {0,0,0,0}, accB[4] = {0,0,0,0};

    for (int p0 = s; p0 < e; p0 += 8) {
        int pA = p0 + slot;
        int pB = p0 + 4 + slot;
        bool vA = (pA < e), vB = (pB < e);
        int2 edA = csr_edge[vA ? pA : s];
        int2 edB = csr_edge[vB ? pB : s];
        int srcA = edA.x, srcB = edB.x;
        union { int u; half2t h; } eA, eB;
        eA.u = edA.y; eB.u = edB.y;
        float eaxA = (float)eA.h[0], eayA = (float)eA.h[1];
        float eaxB = (float)eB.h[0], eayB = (float)eB.h[1];

        half4 hvA = *(const half4*)(xl2h + (size_t)srcA * 64 + 4 * g);
        half4 hvB = *(const half4*)(xl2h + (size_t)srcB * 64 + 4 * g);
        float xlA[4], xlB[4];
#pragma unroll
        for (int i = 0; i < 4; ++i) {
            xlA[i] = (float)hvA[i];
            xlB[i] = (float)hvB[i];
        }

        float pvA = 0.f, pvB = 0.f;
#pragma unroll
        for (int i = 0; i < 4; ++i) {
            float gA = xlA[i] + xr[i] + fmaf(eaxA, w0[i], eayA * w1[i]);
            float gB = xlB[i] + xr[i] + fmaf(eaxB, w0[i], eayB * w1[i]);
            gA = fmaxf(gA, NEG_SLOPE * gA);
            gB = fmaxf(gB, NEG_SLOPE * gB);
            pvA = fmaf(gA, av[i], pvA);
            pvB = fmaf(gB, av[i], pvB);
        }
        pvA += __shfl_xor(pvA, 1);  pvB += __shfl_xor(pvB, 1);
        pvA += __shfl_xor(pvA, 2);  pvB += __shfl_xor(pvB, 2);
        pvA += __shfl_xor(pvA, 4);  pvB += __shfl_xor(pvB, 4);
        pvA += __shfl_xor(pvA, 8);  pvB += __shfl_xor(pvB, 8);
        float evA = vA ? __expf(pvA) : 0.f;
        float evB = vB ? __expf(pvB) : 0.f;
        dA += evA; dB += evB;
#pragma unroll
        for (int i = 0; i < 4; ++i) {
            accA[i] = fmaf(evA, xlA[i], accA[i]);
            accB[i] = fmaf(evB, xlB[i], accB[i]);
        }
    }

    float dsum = dA + dB;
    float acc[4];
#pragma unroll
    for (int i = 0; i < 4; ++i) {
        acc[i] = accA[i] + accB[i];
        acc[i] += __shfl_xor(acc[i], 16);
        acc[i] += __shfl_xor(acc[i], 32);
    }
    dsum += __shfl_xor(dsum, 16);
    dsum += __shfl_xor(dsum, 32);

    float b2[4];
    ld4(b2, bias2 + 4 * g);
    float r = 1.f / (dsum + 1e-16f);
    float h2[4];
#pragma unroll
    for (int i = 0; i < 4; ++i) h2[i] = fmaxf(fmaf(acc[i], r, b2[i]), 0.f);

    // MLP head
    float t = bh1[lane];
#pragma unroll
    for (int gp = 0; gp < 16; ++gp) {
        t = fmaf(__shfl(h2[0], gp), Wh1[(4 * gp + 0) * 64 + lane], t);
        t = fmaf(__shfl(h2[1], gp), Wh1[(4 * gp + 1) * 64 + lane], t);
        t = fmaf(__shfl(h2[2], gp), Wh1[(4 * gp + 2) * 64 + lane], t);
        t = fmaf(__shfl(h2[3], gp), Wh1[(4 * gp + 3) * 64 + lane], t);
    }
    t = fmaxf(t, 0.f);
    float prt = t * Wh2[lane];
#pragma unroll
    for (int o = 32; o; o >>= 1) prt += __shfl_xor(prt, o);
    if (lane == 0) out[n] = prt + bh2[0];
}

// ---------------------------------------------------------------------------
extern "C" void kernel_launch(void* const* d_in, const int* in_sizes, int n_in,
                              void* d_out, int out_size, void* d_ws, size_t ws_size,
                              hipStream_t stream) {
    const float* x    = (const float*)d_in[0];
    const int*   ei   = (const int*)d_in[1];
    const float* ea   = (const float*)d_in[2];
    const float* Wl1  = (const float*)d_in[3];
    const float* bl1  = (const float*)d_in[4];
    const float* Wr1  = (const float*)d_in[5];
    const float* br1  = (const float*)d_in[6];
    const float* We1  = (const float*)d_in[7];
    const float* att1 = (const float*)d_in[8];
    const float* bias1= (const float*)d_in[9];
    const float* Wl2  = (const float*)d_in[10];
    const float* bl2  = (const float*)d_in[11];
    const float* Wr2  = (const float*)d_in[12];
    const float* br2  = (const float*)d_in[13];
    const float* We2  = (const float*)d_in[14];
    const float* att2 = (const float*)d_in[15];
    const float* bias2= (const float*)d_in[16];
    const float* Wh1  = (const float*)d_in[17];
    const float* bh1  = (const float*)d_in[18];
    const float* Wh2  = (const float*)d_in[19];
    const float* bh2  = (const float*)d_in[20];

    int N = in_sizes[0] / 6;
    int E = in_sizes[1] / 2;
    const int* srcv = ei;
    const int* dstv = ei + E;

    // workspace layout
    char* w = (char*)d_ws;
    auto align256 = [](size_t v) { return (v + 255) & ~(size_t)255; };
    _Float16* xlh = (_Float16*)w;
    char* ip = w + align256((size_t)N * 128 * 2);
    _Float16* xrh = (_Float16*)ip; ip += align256((size_t)N * 128 * 2);
    float* h1 = (float*)ip;        ip += align256((size_t)N * 128 * 4);
    _Float16* xl2h = (_Float16*)ip; ip += align256((size_t)N * 64 * 2);
    _Float16* xr2h = (_Float16*)ip; ip += align256((size_t)N * 64 * 2);
    int* deg = (int*)ip;  ip += align256((size_t)N * 4);
    int* off = (int*)ip;  ip += align256((size_t)(N + 1) * 4);
    int* pos = (int*)ip;  ip += align256((size_t)N * 4);
    int B = (N + 511) / 512;
    int* bsum  = (int*)ip; ip += align256((size_t)B * 4);
    int* bpref = (int*)ip; ip += align256((size_t)B * 4);
    int2* csr_edge = (int2*)ip;

    hipMemsetAsync(deg, 0, (size_t)N * sizeof(int), stream);
    prep_kernel<<<((size_t)N * 64 + 255) / 256, 256, 0, stream>>>(
        x, Wl1, bl1, Wr1, br1, xlh, xrh, dstv, deg, N, E);
    scan1_kernel<<<B, 256, 0, stream>>>(deg, bsum, N);
    scan2_kernel<<<1, 256, 0, stream>>>(bsum, bpref, off, B, N);
    scan3_kernel<<<B, 256, 0, stream>>>(deg, bpref, off, pos, N);
    scatter_kernel<<<(E + 255) / 256, 256, 0, stream>>>(
        srcv, dstv, (const float2*)ea, pos, csr_edge, E);
    c1_kernel<<<((size_t)N * 64 + 255) / 256, 256, 0, stream>>>(
        off, csr_edge, xlh, xrh, We1, att1, bias1, h1, N);
    a2_kernel<<<(N + 63) / 64, 256, 0, stream>>>(
        h1, Wl2, bl2, Wr2, br2, xl2h, xr2h, N);
    c2_kernel<<<((size_t)N * 64 + 255) / 256, 256, 0, stream>>>(
        off, csr_edge, xl2h, xr2h, We2, att2, bias2,
        Wh1, bh1, Wh2, bh2, (float*)d_out, N);
}

// Round 7
// 587.666 us; speedup vs baseline: 1.6599x; 1.0343x over previous
//
#include <hip/hip_runtime.h>
#include <hip/hip_bf16.h>

#define NEG_SLOPE 0.2f

typedef _Float16 half8 __attribute__((ext_vector_type(8)));
typedef _Float16 half4 __attribute__((ext_vector_type(4)));
typedef _Float16 half2t __attribute__((ext_vector_type(2)));
typedef float floatx2 __attribute__((ext_vector_type(2)));

__device__ __forceinline__ void ld4(float* d, const float* p) {
    float4 t = *(const float4*)p;
    d[0] = t.x; d[1] = t.y; d[2] = t.z; d[3] = t.w;
}

__device__ __forceinline__ unsigned pack2h(float a, float b) {
    union { half2t h; unsigned u; } pk;
    pk.h[0] = (_Float16)a; pk.h[1] = (_Float16)b;
    return pk.u;
}

// full-rate VALU 16-lane-row all-reduce stage (no DS pipe)
#define DPP_ADD(x, ctrl) \
    ((x) + __int_as_float(__builtin_amdgcn_update_dpp(0, __float_as_int(x), (ctrl), 0xf, 0xf, true)))
// row_ror:8,4,2,1 -> every lane of the 16-lane row gets the row sum
#define ROW_REDUCE16(x) do { \
    x = DPP_ADD(x, 0x128); \
    x = DPP_ADD(x, 0x124); \
    x = DPP_ADD(x, 0x122); \
    x = DPP_ADD(x, 0x121); \
} while (0)

// ---------------------------------------------------------------------------
// PREP: layer-1 source+target transforms -> fp16 interleaved tables + histogram.
// layout: node n, channel c, head h at  n*128 + 2c + h   (fp16)
// ---------------------------------------------------------------------------
__global__ void __launch_bounds__(256) prep_kernel(
    const float* __restrict__ x,
    const float* __restrict__ Wl1, const float* __restrict__ bl1,
    const float* __restrict__ Wr1, const float* __restrict__ br1,
    _Float16* __restrict__ xlh, _Float16* __restrict__ xrh,
    const int* __restrict__ dstv, int* __restrict__ deg,
    int N, int E)
{
    int gt = blockIdx.x * blockDim.x + threadIdx.x;
    int total = blockDim.x * gridDim.x;
    for (int e = gt; e < E; e += total) atomicAdd(&deg[dstv[e]], 1);
    int n = gt >> 6, c = gt & 63;
    if (n >= N) return;
    const float* xrow = x + (size_t)n * 6;
    float l0 = bl1[c], l1 = bl1[64 + c];
    float r0 = br1[c], r1 = br1[64 + c];
#pragma unroll
    for (int f = 0; f < 6; ++f) {
        float xv = xrow[f];
        l0 = fmaf(xv, Wl1[f * 128 + c], l0);
        l1 = fmaf(xv, Wl1[f * 128 + 64 + c], l1);
        r0 = fmaf(xv, Wr1[f * 128 + c], r0);
        r1 = fmaf(xv, Wr1[f * 128 + 64 + c], r1);
    }
    *(unsigned*)(xlh + (size_t)n * 128 + 2 * c) = pack2h(l0, l1);
    *(unsigned*)(xrh + (size_t)n * 128 + 2 * c) = pack2h(r0, r1);
}

// ---------------------------------------------------------------------------
// CSR build: scan + scatter (8B packed edges)
// ---------------------------------------------------------------------------
__global__ void scan1_kernel(const int* __restrict__ deg, int* __restrict__ bsum, int N) {
    __shared__ int red[256];
    int b = blockIdx.x, t = threadIdx.x;
    int i0 = b * 512 + t, i1 = i0 + 256;
    int v = 0;
    if (i0 < N) v += deg[i0];
    if (i1 < N) v += deg[i1];
    red[t] = v;
    __syncthreads();
    for (int s = 128; s > 0; s >>= 1) {
        if (t < s) red[t] += red[t + s];
        __syncthreads();
    }
    if (t == 0) bsum[b] = red[0];
}

__global__ void scan2_kernel(const int* __restrict__ bsum, int* __restrict__ bpref,
                             int* __restrict__ off, int B, int N) {
    __shared__ int lds[1024];
    int t = threadIdx.x;
    for (int i = t; i < B; i += blockDim.x) lds[i] = bsum[i];
    __syncthreads();
    if (t == 0) {
        int run = 0;
        for (int i = 0; i < B; ++i) { int v = lds[i]; lds[i] = run; run += v; }
        off[N] = run;
    }
    __syncthreads();
    for (int i = t; i < B; i += blockDim.x) bpref[i] = lds[i];
}

__global__ void scan3_kernel(const int* __restrict__ deg, const int* __restrict__ bpref,
                             int* __restrict__ off, int* __restrict__ pos, int N) {
    __shared__ int lds[512];
    int b = blockIdx.x, t = threadIdx.x;
    int base = b * 512;
    for (int i = t; i < 512; i += 256) {
        int g = base + i;
        lds[i] = (g < N) ? deg[g] : 0;
    }
    __syncthreads();
    if (t == 0) {
        int run = bpref[b];
        for (int i = 0; i < 512; ++i) { int v = lds[i]; lds[i] = run; run += v; }
    }
    __syncthreads();
    for (int i = t; i < 512; i += 256) {
        int g = base + i;
        if (g < N) { off[g] = lds[i]; pos[g] = lds[i]; }
    }
}

// 8B per edge: {src, half2(ea.x, ea.y)}
__global__ void scatter_kernel(const int* __restrict__ srcv, const int* __restrict__ dstv,
                               const float2* __restrict__ ea2, int* __restrict__ pos,
                               int2* __restrict__ csr_edge, int E) {
    int e = blockIdx.x * blockDim.x + threadIdx.x;
    if (e >= E) return;
    int d = dstv[e];
    int p = atomicAdd(&pos[d], 1);
    float2 ea = ea2[e];
    int2 v;
    v.x = srcv[e];
    v.y = (int)pack2h(ea.x, ea.y);
    csr_edge[p] = v;
}

// ---------------------------------------------------------------------------
// C1: layer-1 aggregation. Wave per dst node; 8 edges/iter (2 quads x 16
// lanes/edge). DPP row-reduce for logits, packed float2 channel math.
// ---------------------------------------------------------------------------
__global__ void __launch_bounds__(256) c1_kernel(
    const int* __restrict__ off, const int2* __restrict__ csr_edge,
    const _Float16* __restrict__ xlh, const _Float16* __restrict__ xrh,
    const float* __restrict__ We1, const float* __restrict__ att1,
    const float* __restrict__ bias1,
    float* __restrict__ h1, int N)
{
    int wid = (blockIdx.x * blockDim.x + threadIdx.x) >> 6;
    int lane = threadIdx.x & 63;
    if (wid >= N) return;
    int n = wid;
    int g = lane & 15;
    int slot = lane >> 4;

    floatx2 a0v[2], a1v[2], w00v[2], w01v[2], w10v[2], w11v[2];
    {
        float t[4];
        ld4(t, att1 + 4 * g);       a0v[0] = floatx2{t[0], t[1]}; a0v[1] = floatx2{t[2], t[3]};
        ld4(t, att1 + 64 + 4 * g);  a1v[0] = floatx2{t[0], t[1]}; a1v[1] = floatx2{t[2], t[3]};
        ld4(t, We1 + 4 * g);        w00v[0] = floatx2{t[0], t[1]}; w00v[1] = floatx2{t[2], t[3]};
        ld4(t, We1 + 64 + 4 * g);   w01v[0] = floatx2{t[0], t[1]}; w01v[1] = floatx2{t[2], t[3]};
        ld4(t, We1 + 128 + 4 * g);  w10v[0] = floatx2{t[0], t[1]}; w10v[1] = floatx2{t[2], t[3]};
        ld4(t, We1 + 192 + 4 * g);  w11v[0] = floatx2{t[0], t[1]}; w11v[1] = floatx2{t[2], t[3]};
    }

    floatx2 xr0v[2], xr1v[2];
    {
        half8 xrv = *(const half8*)(xrh + (size_t)n * 128 + 8 * g);
        xr0v[0] = floatx2{(float)xrv[0], (float)xrv[2]};
        xr0v[1] = floatx2{(float)xrv[4], (float)xrv[6]};
        xr1v[0] = floatx2{(float)xrv[1], (float)xrv[3]};
        xr1v[1] = floatx2{(float)xrv[5], (float)xrv[7]};
    }

    int s = off[n], e = off[n + 1];
    floatx2 acc0A[2] = {floatx2{0,0}, floatx2{0,0}}, acc1A[2] = {floatx2{0,0}, floatx2{0,0}};
    floatx2 acc0B[2] = {floatx2{0,0}, floatx2{0,0}}, acc1B[2] = {floatx2{0,0}, floatx2{0,0}};
    float d0A = 0.f, d1A = 0.f, d0B = 0.f, d1B = 0.f;

    for (int p0 = s; p0 < e; p0 += 8) {
        int pA = p0 + slot;
        int pB = p0 + 4 + slot;
        bool vA = (pA < e), vB = (pB < e);
        int2 edA = csr_edge[vA ? pA : s];
        int2 edB = csr_edge[vB ? pB : s];
        int srcA = edA.x, srcB = edB.x;
        union { int u; half2t h; } eAu, eBu;
        eAu.u = edA.y; eBu.u = edB.y;
        float eaxA = (float)eAu.h[0], eayA = (float)eAu.h[1];
        float eaxB = (float)eBu.h[0], eayB = (float)eBu.h[1];

        half8 hvA = *(const half8*)(xlh + (size_t)srcA * 128 + 8 * g);
        half8 hvB = *(const half8*)(xlh + (size_t)srcB * 128 + 8 * g);

        floatx2 xl0A[2], xl1A[2], xl0B[2], xl1B[2];
        xl0A[0] = floatx2{(float)hvA[0], (float)hvA[2]};
        xl0A[1] = floatx2{(float)hvA[4], (float)hvA[6]};
        xl1A[0] = floatx2{(float)hvA[1], (float)hvA[3]};
        xl1A[1] = floatx2{(float)hvA[5], (float)hvA[7]};
        xl0B[0] = floatx2{(float)hvB[0], (float)hvB[2]};
        xl0B[1] = floatx2{(float)hvB[4], (float)hvB[6]};
        xl1B[0] = floatx2{(float)hvB[1], (float)hvB[3]};
        xl1B[1] = floatx2{(float)hvB[5], (float)hvB[7]};

        floatx2 pv0A = floatx2{0,0}, pv1A = floatx2{0,0};
        floatx2 pv0B = floatx2{0,0}, pv1B = floatx2{0,0};
#pragma unroll
        for (int k = 0; k < 2; ++k) {
            floatx2 z;
            z = xl0A[k] + xr0v[k];
            z = __builtin_elementwise_fma((floatx2)eaxA, w00v[k], z);
            z = __builtin_elementwise_fma((floatx2)eayA, w10v[k], z);
            z = __builtin_elementwise_max(z, z * (floatx2)NEG_SLOPE);
            pv0A = __builtin_elementwise_fma(z, a0v[k], pv0A);

            z = xl1A[k] + xr1v[k];
            z = __builtin_elementwise_fma((floatx2)eaxA, w01v[k], z);
            z = __builtin_elementwise_fma((floatx2)eayA, w11v[k], z);
            z = __builtin_elementwise_max(z, z * (floatx2)NEG_SLOPE);
            pv1A = __builtin_elementwise_fma(z, a1v[k], pv1A);

            z = xl0B[k] + xr0v[k];
            z = __builtin_elementwise_fma((floatx2)eaxB, w00v[k], z);
            z = __builtin_elementwise_fma((floatx2)eayB, w10v[k], z);
            z = __builtin_elementwise_max(z, z * (floatx2)NEG_SLOPE);
            pv0B = __builtin_elementwise_fma(z, a0v[k], pv0B);

            z = xl1B[k] + xr1v[k];
            z = __builtin_elementwise_fma((floatx2)eaxB, w01v[k], z);
            z = __builtin_elementwise_fma((floatx2)eayB, w11v[k], z);
            z = __builtin_elementwise_max(z, z * (floatx2)NEG_SLOPE);
            pv1B = __builtin_elementwise_fma(z, a1v[k], pv1B);
        }
        float pA0 = pv0A.x + pv0A.y;
        float pA1 = pv1A.x + pv1A.y;
        float pB0 = pv0B.x + pv0B.y;
        float pB1 = pv1B.x + pv1B.y;

        // 16-lane-row all-reduce, pure VALU (DPP), 4 independent chains
        ROW_REDUCE16(pA0);
        ROW_REDUCE16(pA1);
        ROW_REDUCE16(pB0);
        ROW_REDUCE16(pB1);

        float eA0 = vA ? __expf(pA0) : 0.f;
        float eA1 = vA ? __expf(pA1) : 0.f;
        float eB0 = vB ? __expf(pB0) : 0.f;
        float eB1 = vB ? __expf(pB1) : 0.f;
        d0A += eA0; d1A += eA1;
        d0B += eB0; d1B += eB1;
#pragma unroll
        for (int k = 0; k < 2; ++k) {
            acc0A[k] = __builtin_elementwise_fma((floatx2)eA0, xl0A[k], acc0A[k]);
            acc1A[k] = __builtin_elementwise_fma((floatx2)eA1, xl1A[k], acc1A[k]);
            acc0B[k] = __builtin_elementwise_fma((floatx2)eB0, xl0B[k], acc0B[k]);
            acc1B[k] = __builtin_elementwise_fma((floatx2)eB1, xl1B[k], acc1B[k]);
        }
    }

    // merge quads, then cross-row reduce (once per wave)
    float acc0[4], acc1[4];
    acc0[0] = acc0A[0].x + acc0B[0].x;  acc0[1] = acc0A[0].y + acc0B[0].y;
    acc0[2] = acc0A[1].x + acc0B[1].x;  acc0[3] = acc0A[1].y + acc0B[1].y;
    acc1[0] = acc1A[0].x + acc1B[0].x;  acc1[1] = acc1A[0].y + acc1B[0].y;
    acc1[2] = acc1A[1].x + acc1B[1].x;  acc1[3] = acc1A[1].y + acc1B[1].y;
    float d0 = d0A + d0B, d1 = d1A + d1B;
#pragma unroll
    for (int i = 0; i < 4; ++i) {
        acc0[i] += __shfl_xor(acc0[i], 16); acc0[i] += __shfl_xor(acc0[i], 32);
        acc1[i] += __shfl_xor(acc1[i], 16); acc1[i] += __shfl_xor(acc1[i], 32);
    }
    d0 += __shfl_xor(d0, 16); d0 += __shfl_xor(d0, 32);
    d1 += __shfl_xor(d1, 16); d1 += __shfl_xor(d1, 32);

    if (slot == 0) {
        float b0[4], b1[4];
        ld4(b0, bias1 + 4 * g);
        ld4(b1, bias1 + 64 + 4 * g);
        float r0 = 1.f / (d0 + 1e-16f), r1 = 1.f / (d1 + 1e-16f);
        float4 o0, o1;
        o0.x = fmaxf(fmaf(acc0[0], r0, b0[0]), 0.f);
        o0.y = fmaxf(fmaf(acc0[1], r0, b0[1]), 0.f);
        o0.z = fmaxf(fmaf(acc0[2], r0, b0[2]), 0.f);
        o0.w = fmaxf(fmaf(acc0[3], r0, b0[3]), 0.f);
        o1.x = fmaxf(fmaf(acc1[0], r1, b1[0]), 0.f);
        o1.y = fmaxf(fmaf(acc1[1], r1, b1[1]), 0.f);
        o1.z = fmaxf(fmaf(acc1[2], r1, b1[2]), 0.f);
        o1.w = fmaxf(fmaf(acc1[3], r1, b1[3]), 0.f);
        *(float4*)(h1 + (size_t)n * 128 + 4 * g) = o0;
        *(float4*)(h1 + (size_t)n * 128 + 64 + 4 * g) = o1;
    }
}

// ---------------------------------------------------------------------------
// A2: layer-2 node transforms as an LDS-tiled GEMM (no shuffles).
// ---------------------------------------------------------------------------
__global__ void __launch_bounds__(256) a2_kernel(
    const float* __restrict__ h1,
    const float* __restrict__ Wl2, const float* __restrict__ bl2,
    const float* __restrict__ Wr2, const float* __restrict__ br2,
    _Float16* __restrict__ xl2h, _Float16* __restrict__ xr2h, int N)
{
    __shared__ float hs[64 * 128];   // 32 KB
    int tid = threadIdx.x;
    int n0 = blockIdx.x * 64;

    for (int i = tid; i < 64 * 32; i += 256) {
        int row = i >> 5;
        int q = i & 31;
        int n = n0 + row;
        float4 v = (n < N) ? *(const float4*)(h1 + (size_t)n * 128 + q * 4)
                           : make_float4(0.f, 0.f, 0.f, 0.f);
        *(float4*)(hs + row * 128 + q * 4) = v;
    }
    __syncthreads();

    int cslot = tid & 31;
    int jgrp = tid >> 5;
    int c4 = cslot * 4;
    bool isL = (c4 < 64);
    int cc = isL ? c4 : (c4 - 64);
    const float* Wb = (isL ? Wl2 : Wr2) + cc;
    const float* bb = (isL ? bl2 : br2) + cc;
    float4 bias = *(const float4*)bb;

    float acc[8][4];
#pragma unroll
    for (int j = 0; j < 8; ++j) {
        acc[j][0] = bias.x; acc[j][1] = bias.y;
        acc[j][2] = bias.z; acc[j][3] = bias.w;
    }

    const float* hrow = hs + (jgrp * 8) * 128;
#pragma unroll 2
    for (int k4 = 0; k4 < 32; ++k4) {
        float4 w0 = *(const float4*)(Wb + (4 * k4 + 0) * 64);
        float4 w1 = *(const float4*)(Wb + (4 * k4 + 1) * 64);
        float4 w2 = *(const float4*)(Wb + (4 * k4 + 2) * 64);
        float4 w3 = *(const float4*)(Wb + (4 * k4 + 3) * 64);
#pragma unroll
        for (int j = 0; j < 8; ++j) {
            float4 hv = *(const float4*)(hrow + j * 128 + k4 * 4);
            acc[j][0] = fmaf(hv.x, w0.x, acc[j][0]);
            acc[j][1] = fmaf(hv.x, w0.y, acc[j][1]);
            acc[j][2] = fmaf(hv.x, w0.z, acc[j][2]);
            acc[j][3] = fmaf(hv.x, w0.w, acc[j][3]);
            acc[j][0] = fmaf(hv.y, w1.x, acc[j][0]);
            acc[j][1] = fmaf(hv.y, w1.y, acc[j][1]);
            acc[j][2] = fmaf(hv.y, w1.z, acc[j][2]);
            acc[j][3] = fmaf(hv.y, w1.w, acc[j][3]);
            acc[j][0] = fmaf(hv.z, w2.x, acc[j][0]);
            acc[j][1] = fmaf(hv.z, w2.y, acc[j][1]);
            acc[j][2] = fmaf(hv.z, w2.z, acc[j][2]);
            acc[j][3] = fmaf(hv.z, w2.w, acc[j][3]);
            acc[j][0] = fmaf(hv.w, w3.x, acc[j][0]);
            acc[j][1] = fmaf(hv.w, w3.y, acc[j][1]);
            acc[j][2] = fmaf(hv.w, w3.z, acc[j][2]);
            acc[j][3] = fmaf(hv.w, w3.w, acc[j][3]);
        }
    }

    _Float16* outb = isL ? xl2h : xr2h;
#pragma unroll
    for (int j = 0; j < 8; ++j) {
        int n = n0 + jgrp * 8 + j;
        if (n < N) {
            half4 o;
            o[0] = (_Float16)acc[j][0];
            o[1] = (_Float16)acc[j][1];
            o[2] = (_Float16)acc[j][2];
            o[3] = (_Float16)acc[j][3];
            *(half4*)(outb + (size_t)n * 64 + cc) = o;
        }
    }
}

// ---------------------------------------------------------------------------
// C2: layer-2 aggregation + fused MLP head. DPP row-reduce, packed math.
// ---------------------------------------------------------------------------
__global__ void __launch_bounds__(256) c2_kernel(
    const int* __restrict__ off, const int2* __restrict__ csr_edge,
    const _Float16* __restrict__ xl2h, const _Float16* __restrict__ xr2h,
    const float* __restrict__ We2, const float* __restrict__ att2,
    const float* __restrict__ bias2,
    const float* __restrict__ Wh1, const float* __restrict__ bh1,
    const float* __restrict__ Wh2, const float* __restrict__ bh2,
    float* __restrict__ out, int N)
{
    int wid = (blockIdx.x * blockDim.x + threadIdx.x) >> 6;
    int lane = threadIdx.x & 63;
    if (wid >= N) return;
    int n = wid;
    int g = lane & 15;
    int slot = lane >> 4;

    floatx2 avv[2], w0v[2], w1v[2], xrv[2];
    {
        float t[4];
        ld4(t, att2 + 4 * g);      avv[0] = floatx2{t[0], t[1]}; avv[1] = floatx2{t[2], t[3]};
        ld4(t, We2 + 4 * g);       w0v[0] = floatx2{t[0], t[1]}; w0v[1] = floatx2{t[2], t[3]};
        ld4(t, We2 + 64 + 4 * g);  w1v[0] = floatx2{t[0], t[1]}; w1v[1] = floatx2{t[2], t[3]};
        half4 xh = *(const half4*)(xr2h + (size_t)n * 64 + 4 * g);
        xrv[0] = floatx2{(float)xh[0], (float)xh[1]};
        xrv[1] = floatx2{(float)xh[2], (float)xh[3]};
    }

    int s = off[n], e = off[n + 1];
    float dA = 0.f, dB = 0.f;
    floatx2 accA[2] = {floatx2{0,0}, floatx2{0,0}};
    floatx2 accB[2] = {floatx2{0,0}, floatx2{0,0}};

    for (int p0 = s; p0 < e; p0 += 8) {
        int pA = p0 + slot;
        int pB = p0 + 4 + slot;
        bool vA = (pA < e), vB = (pB < e);
        int2 edA = csr_edge[vA ? pA : s];
        int2 edB = csr_edge[vB ? pB : s];
        int srcA = edA.x, srcB = edB.x;
        union { int u; half2t h; } eAu, eBu;
        eAu.u = edA.y; eBu.u = edB.y;
        float eaxA = (float)eAu.h[0], eayA = (float)eAu.h[1];
        float eaxB = (float)eBu.h[0], eayB = (float)eBu.h[1];

        half4 hvA = *(const half4*)(xl2h + (size_t)srcA * 64 + 4 * g);
        half4 hvB = *(const half4*)(xl2h + (size_t)srcB * 64 + 4 * g);
        floatx2 xlA[2], xlB[2];
        xlA[0] = floatx2{(float)hvA[0], (float)hvA[1]};
        xlA[1] = floatx2{(float)hvA[2], (float)hvA[3]};
        xlB[0] = floatx2{(float)hvB[0], (float)hvB[1]};
        xlB[1] = floatx2{(float)hvB[2], (float)hvB[3]};

        floatx2 pvA = floatx2{0,0}, pvB = floatx2{0,0};
#pragma unroll
        for (int k = 0; k < 2; ++k) {
            floatx2 z;
            z = xlA[k] + xrv[k];
            z = __builtin_elementwise_fma((floatx2)eaxA, w0v[k], z);
            z = __builtin_elementwise_fma((floatx2)eayA, w1v[k], z);
            z = __builtin_elementwise_max(z, z * (floatx2)NEG_SLOPE);
            pvA = __builtin_elementwise_fma(z, avv[k], pvA);

            z = xlB[k] + xrv[k];
            z = __builtin_elementwise_fma((floatx2)eaxB, w0v[k], z);
            z = __builtin_elementwise_fma((floatx2)eayB, w1v[k], z);
            z = __builtin_elementwise_max(z, z * (floatx2)NEG_SLOPE);
            pvB = __builtin_elementwise_fma(z, avv[k], pvB);
        }
        float pA_ = pvA.x + pvA.y;
        float pB_ = pvB.x + pvB.y;
        ROW_REDUCE16(pA_);
        ROW_REDUCE16(pB_);
        float evA = vA ? __expf(pA_) : 0.f;
        float evB = vB ? __expf(pB_) : 0.f;
        dA += evA; dB += evB;
#pragma unroll
        for (int k = 0; k < 2; ++k) {
            accA[k] = __builtin_elementwise_fma((floatx2)evA, xlA[k], accA[k]);
            accB[k] = __builtin_elementwise_fma((floatx2)evB, xlB[k], accB[k]);
        }
    }

    float acc[4];
    acc[0] = accA[0].x + accB[0].x;  acc[1] = accA[0].y + accB[0].y;
    acc[2] = accA[1].x + accB[1].x;  acc[3] = accA[1].y + accB[1].y;
    float dsum = dA + dB;
#pragma unroll
    for (int i = 0; i < 4; ++i) {
        acc[i] += __shfl_xor(acc[i], 16);
        acc[i] += __shfl_xor(acc[i], 32);
    }
    dsum += __shfl_xor(dsum, 16);
    dsum += __shfl_xor(dsum, 32);

    float b2[4];
    ld4(b2, bias2 + 4 * g);
    float r = 1.f / (dsum + 1e-16f);
    float h2[4];
#pragma unroll
    for (int i = 0; i < 4; ++i) h2[i] = fmaxf(fmaf(acc[i], r, b2[i]), 0.f);

    // MLP head
    float t = bh1[lane];
#pragma unroll
    for (int gp = 0; gp < 16; ++gp) {
        t = fmaf(__shfl(h2[0], gp), Wh1[(4 * gp + 0) * 64 + lane], t);
        t = fmaf(__shfl(h2[1], gp), Wh1[(4 * gp + 1) * 64 + lane], t);
        t = fmaf(__shfl(h2[2], gp), Wh1[(4 * gp + 2) * 64 + lane], t);
        t = fmaf(__shfl(h2[3], gp), Wh1[(4 * gp + 3) * 64 + lane], t);
    }
    t = fmaxf(t, 0.f);
    float prt = t * Wh2[lane];
#pragma unroll
    for (int o = 32; o; o >>= 1) prt += __shfl_xor(prt, o);
    if (lane == 0) out[n] = prt + bh2[0];
}

// ---------------------------------------------------------------------------
extern "C" void kernel_launch(void* const* d_in, const int* in_sizes, int n_in,
                              void* d_out, int out_size, void* d_ws, size_t ws_size,
                              hipStream_t stream) {
    const float* x    = (const float*)d_in[0];
    const int*   ei   = (const int*)d_in[1];
    const float* ea   = (const float*)d_in[2];
    const float* Wl1  = (const float*)d_in[3];
    const float* bl1  = (const float*)d_in[4];
    const float* Wr1  = (const float*)d_in[5];
    const float* br1  = (const float*)d_in[6];
    const float* We1  = (const float*)d_in[7];
    const float* att1 = (const float*)d_in[8];
    const float* bias1= (const float*)d_in[9];
    const float* Wl2  = (const float*)d_in[10];
    const float* bl2  = (const float*)d_in[11];
    const float* Wr2  = (const float*)d_in[12];
    const float* br2  = (const float*)d_in[13];
    const float* We2  = (const float*)d_in[14];
    const float* att2 = (const float*)d_in[15];
    const float* bias2= (const float*)d_in[16];
    const float* Wh1  = (const float*)d_in[17];
    const float* bh1  = (const float*)d_in[18];
    const float* Wh2  = (const float*)d_in[19];
    const float* bh2  = (const float*)d_in[20];

    int N = in_sizes[0] / 6;
    int E = in_sizes[1] / 2;
    const int* srcv = ei;
    const int* dstv = ei + E;

    char* w = (char*)d_ws;
    auto align256 = [](size_t v) { return (v + 255) & ~(size_t)255; };
    _Float16* xlh = (_Float16*)w;
    char* ip = w + align256((size_t)N * 128 * 2);
    _Float16* xrh = (_Float16*)ip; ip += align256((size_t)N * 128 * 2);
    float* h1 = (float*)ip;        ip += align256((size_t)N * 128 * 4);
    _Float16* xl2h = (_Float16*)ip; ip += align256((size_t)N * 64 * 2);
    _Float16* xr2h = (_Float16*)ip; ip += align256((size_t)N * 64 * 2);
    int* deg = (int*)ip;  ip += align256((size_t)N * 4);
    int* off = (int*)ip;  ip += align256((size_t)(N + 1) * 4);
    int* pos = (int*)ip;  ip += align256((size_t)N * 4);
    int B = (N + 511) / 512;
    int* bsum  = (int*)ip; ip += align256((size_t)B * 4);
    int* bpref = (int*)ip; ip += align256((size_t)B * 4);
    int2* csr_edge = (int2*)ip;

    hipMemsetAsync(deg, 0, (size_t)N * sizeof(int), stream);
    prep_kernel<<<((size_t)N * 64 + 255) / 256, 256, 0, stream>>>(
        x, Wl1, bl1, Wr1, br1, xlh, xrh, dstv, deg, N, E);
    scan1_kernel<<<B, 256, 0, stream>>>(deg, bsum, N);
    scan2_kernel<<<1, 256, 0, stream>>>(bsum, bpref, off, B, N);
    scan3_kernel<<<B, 256, 0, stream>>>(deg, bpref, off, pos, N);
    scatter_kernel<<<(E + 255) / 256, 256, 0, stream>>>(
        srcv, dstv, (const float2*)ea, pos, csr_edge, E);
    c1_kernel<<<((size_t)N * 64 + 255) / 256, 256, 0, stream>>>(
        off, csr_edge, xlh, xrh, We1, att1, bias1, h1, N);
    a2_kernel<<<(N + 63) / 64, 256, 0, stream>>>(
        h1, Wl2, bl2, Wr2, br2, xl2h, xr2h, N);
    c2_kernel<<<((size_t)N * 64 + 255) / 256, 256, 0, stream>>>(
        off, csr_edge, xl2h, xr2h, We2, att2, bias2,
        Wh1, bh1, Wh2, bh2, (float*)d_out, N);
}